// Round 1
// baseline (5508.244 us; speedup 1.0000x reference)
//
#include <hip/hip_runtime.h>
#include <math.h>

// MixAxialPOLABlock — round 1: correctness-first fp32 implementation.
// B=4, H=W=112, C=256 = [local 128 | vert-axial 64 | horz-axial 64]
// ws usage: NTOK*(256 + 4*128 + 8*64) floats = 256,901,120 bytes (~245 MiB).

namespace {

constexpr int IMG  = 112;
constexpr int NTOK = 4 * IMG * IMG;   // 50176
constexpr int CDIM = 256;
constexpr int LCH  = 128;
constexpr int ACH  = 64;
constexpr float QSC = 0.17677669529663687f;  // 1/sqrt(32)

// ---------------- LayerNorm (ln1) : one block per token ----------------
__global__ __launch_bounds__(256) void ln1_kernel(
    const float* __restrict__ x, const float* __restrict__ w,
    const float* __restrict__ b, float* __restrict__ out)
{
  int tok = blockIdx.x;
  int c = threadIdx.x;
  size_t idx = (size_t)tok * CDIM + c;
  float v = x[idx];
  float s = v, s2 = v * v;
  #pragma unroll
  for (int o = 32; o; o >>= 1) { s += __shfl_xor(s, o); s2 += __shfl_xor(s2, o); }
  __shared__ float red[8];
  int lane = c & 63, wv = c >> 6;
  if (lane == 0) { red[wv] = s; red[4 + wv] = s2; }
  __syncthreads();
  float a  = red[0] + red[1] + red[2] + red[3];
  float a2 = red[4] + red[5] + red[6] + red[7];
  float mu  = a * (1.f / CDIM);
  float var = a2 * (1.f / CDIM) - mu * mu;
  float rs  = rsqrtf(var + 1e-5f);
  out[idx] = (v - mu) * rs * w[c] + b[c];
}

// ------------- fused q/k/v projection for one channel group -------------
// IN == OUT (square weights). q gets (acc+bias)*qscale, k/v just +bias.
template<int IN>
__global__ __launch_bounds__(256) void qkv_kernel(
    const float* __restrict__ h1, int in_off,
    const float* __restrict__ wq, const float* __restrict__ bq,
    const float* __restrict__ wk, const float* __restrict__ bk,
    const float* __restrict__ wv, const float* __restrict__ bv,
    float* __restrict__ qo, float* __restrict__ ko, float* __restrict__ vo,
    float qscale)
{
  constexpr int TM = 4;
  __shared__ float rows[TM][IN];
  int t0 = blockIdx.x * TM;
  for (int i = threadIdx.x; i < TM * IN; i += 256) {
    int t = i / IN, k = i % IN;
    rows[t][k] = h1[(size_t)(t0 + t) * CDIM + in_off + k];
  }
  __syncthreads();
  for (int o = threadIdx.x; o < 3 * IN; o += 256) {
    int sel = o / IN, col = o % IN;
    const float* wm = sel == 0 ? wq : (sel == 1 ? wk : wv);
    const float* bm = sel == 0 ? bq : (sel == 1 ? bk : bv);
    float sc = (sel == 0) ? qscale : 1.0f;
    float acc[TM];
    #pragma unroll
    for (int t = 0; t < TM; t++) acc[t] = 0.f;
    for (int k = 0; k < IN; k++) {
      float wval = wm[(size_t)k * IN + col];
      #pragma unroll
      for (int t = 0; t < TM; t++) acc[t] += rows[t][k] * wval;
    }
    float* op = sel == 0 ? qo : (sel == 1 ? ko : vo);
    #pragma unroll
    for (int t = 0; t < TM; t++)
      op[(size_t)(t0 + t) * IN + col] = (acc[t] + bm[col]) * sc;
  }
}

// ---------------- local window attention ----------------
// block = (window, head); 4 waves, each wave serves one query at a time.
// OOB keys of the padded 21x21 neighborhood use k=bk, v=bv (projection of 0).
__global__ __launch_bounds__(256) void loc_attn_kernel(
    const float* __restrict__ ql, const float* __restrict__ kl,
    const float* __restrict__ vl, const float* __restrict__ bk,
    const float* __restrict__ bv, const float* __restrict__ btbl,
    float* __restrict__ ol)
{
  int head = blockIdx.x & 3;
  int wi = blockIdx.x >> 2;                 // 0..1023
  int wx = wi & 15, wy = (wi >> 4) & 15, b = wi >> 8;
  int lane = threadIdx.x & 63, wvid = threadIdx.x >> 6;
  __shared__ float qs[4][32];
  __shared__ float probs[4][441];
  const float* bkh = bk + head * 32;
  const float* bvh = bv + head * 32;

  for (int qi = wvid; qi < 52; qi += 4) {   // 13 uniform iterations per wave
    bool active = qi < 49;
    int qy = qi / 7, qx = qi % 7;
    int py = wy * 7 + qy, px = wx * 7 + qx;
    size_t qbase = ((size_t)((b * IMG + py) * IMG + px)) * LCH + head * 32;
    __syncthreads();                        // protect qs/probs of prev iter
    if (active && lane < 32) qs[wvid][lane] = ql[qbase + lane];
    __syncthreads();
    float qreg[32];
    #pragma unroll
    for (int d = 0; d < 32; d++) qreg[d] = qs[wvid][d];

    float lg[7];
    float m = -1e30f;
    if (active) {
      #pragma unroll
      for (int jj = 0; jj < 7; jj++) {
        int j = jj * 64 + lane;
        if (j < 441) {
          int ky = j / 21, kx = j % 21;
          int r = wy * 7 + ky - 7, c = wx * 7 + kx - 7;
          bool inb = ((unsigned)r < (unsigned)IMG) && ((unsigned)c < (unsigned)IMG);
          const float* kp = inb ? (kl + ((size_t)((b * IMG + r) * IMG + c)) * LCH + head * 32)
                                : bkh;
          float acc = 0.f;
          #pragma unroll
          for (int d = 0; d < 32; d++) acc += qreg[d] * kp[d];
          int dy = qy - ky + 20, dx = qx - kx + 20;
          acc += btbl[(dy * 27 + dx) * 4 + head];
          lg[jj] = acc;
          m = fmaxf(m, acc);
        }
      }
    }
    #pragma unroll
    for (int o = 32; o; o >>= 1) m = fmaxf(m, __shfl_xor(m, o));
    float ssum = 0.f;
    if (active) {
      #pragma unroll
      for (int jj = 0; jj < 7; jj++) {
        int j = jj * 64 + lane;
        if (j < 441) {
          float p = __expf(lg[jj] - m);
          probs[wvid][j] = p;
          ssum += p;
        }
      }
    }
    #pragma unroll
    for (int o = 32; o; o >>= 1) ssum += __shfl_xor(ssum, o);
    float inv = 1.f / ssum;
    __syncthreads();                        // probs visible wave-wide
    int d = lane & 31, half = lane >> 5;
    float acc = 0.f;
    if (active) {
      for (int j = half; j < 441; j += 2) {
        int ky = j / 21, kx = j % 21;
        int r = wy * 7 + ky - 7, c = wx * 7 + kx - 7;
        bool inb = ((unsigned)r < (unsigned)IMG) && ((unsigned)c < (unsigned)IMG);
        const float* vp = inb ? (vl + ((size_t)((b * IMG + r) * IMG + c)) * LCH + head * 32)
                              : bvh;
        acc += probs[wvid][j] * vp[d];
      }
    }
    acc += __shfl_xor(acc, 32);
    if (active && half == 0) ol[qbase + d] = acc * inv;
  }
}

// ---------------- axial attention (vert: over h; horz: over w) ----------------
__global__ __launch_bounds__(256) void axial_attn_kernel(
    const float* __restrict__ q, const float* __restrict__ k,
    const float* __restrict__ v, float* __restrict__ out, int vert)
{
  int head = blockIdx.x & 1;
  int s = blockIdx.x >> 1;                  // 0..447
  int b = s / IMG, t = s % IMG;             // t = w (vert) or h (horz)
  size_t base; int stride;
  if (vert) { base = ((size_t)b * IMG * IMG + t) * ACH; stride = IMG * ACH; }
  else      { base = ((size_t)(b * IMG + t)) * (size_t)IMG * ACH; stride = ACH; }
  base += head * 32;
  int lane = threadIdx.x & 63, wvid = threadIdx.x >> 6;
  __shared__ float qs[4][32];
  __shared__ float probs[4][112];

  for (int qi = wvid; qi < IMG; qi += 4) {  // 28 uniform iterations
    __syncthreads();
    if (lane < 32) qs[wvid][lane] = q[base + (size_t)qi * stride + lane];
    __syncthreads();
    float qreg[32];
    #pragma unroll
    for (int d = 0; d < 32; d++) qreg[d] = qs[wvid][d];
    float lg[2];
    float m = -1e30f;
    #pragma unroll
    for (int jj = 0; jj < 2; jj++) {
      int j = jj * 64 + lane;
      if (j < IMG) {
        const float* kp = k + base + (size_t)j * stride;
        float acc = 0.f;
        #pragma unroll
        for (int d = 0; d < 32; d++) acc += qreg[d] * kp[d];
        lg[jj] = acc;
        m = fmaxf(m, acc);
      }
    }
    #pragma unroll
    for (int o = 32; o; o >>= 1) m = fmaxf(m, __shfl_xor(m, o));
    float ssum = 0.f;
    #pragma unroll
    for (int jj = 0; jj < 2; jj++) {
      int j = jj * 64 + lane;
      if (j < IMG) {
        float p = __expf(lg[jj] - m);
        probs[wvid][j] = p;
        ssum += p;
      }
    }
    #pragma unroll
    for (int o = 32; o; o >>= 1) ssum += __shfl_xor(ssum, o);
    float inv = 1.f / ssum;
    __syncthreads();
    int d = lane & 31, half = lane >> 5;
    float acc = 0.f;
    for (int j = half; j < IMG; j += 2)
      acc += probs[wvid][j] * v[base + (size_t)j * stride + d];
    acc += __shfl_xor(acc, 32);
    if (half == 0) out[base + (size_t)qi * stride + d] = acc * inv;
  }
}

// ------------- output projections + residual concat → x2 (in d_out) -------------
__global__ __launch_bounds__(256) void proj_res_kernel(
    const float* __restrict__ x, const float* __restrict__ ol,
    const float* __restrict__ ov, const float* __restrict__ oh,
    const float* __restrict__ wpl, const float* __restrict__ bpl,
    const float* __restrict__ wpv, const float* __restrict__ bpv,
    const float* __restrict__ wph, const float* __restrict__ bph,
    float* __restrict__ x2)
{
  constexpr int TM = 4;
  __shared__ float rl[TM][LCH];
  __shared__ float rv[TM][ACH];
  __shared__ float rh[TM][ACH];
  int t0 = blockIdx.x * TM;
  for (int i = threadIdx.x; i < TM * LCH; i += 256) {
    int t = i >> 7, c = i & 127;
    rl[t][c] = ol[(size_t)(t0 + t) * LCH + c];
  }
  for (int i = threadIdx.x; i < TM * ACH; i += 256) {
    int t = i >> 6, c = i & 63;
    rv[t][c] = ov[(size_t)(t0 + t) * ACH + c];
    rh[t][c] = oh[(size_t)(t0 + t) * ACH + c];
  }
  __syncthreads();
  int c = threadIdx.x;
  float acc[TM];
  if (c < 128) {
    #pragma unroll
    for (int t = 0; t < TM; t++) acc[t] = bpl[c];
    for (int kk = 0; kk < LCH; kk++) {
      float wval = wpl[(size_t)kk * LCH + c];
      #pragma unroll
      for (int t = 0; t < TM; t++) acc[t] += rl[t][kk] * wval;
    }
  } else if (c < 192) {
    int cc = c - 128;
    #pragma unroll
    for (int t = 0; t < TM; t++) acc[t] = bpv[cc];
    for (int kk = 0; kk < ACH; kk++) {
      float wval = wpv[(size_t)kk * ACH + cc];
      #pragma unroll
      for (int t = 0; t < TM; t++) acc[t] += rv[t][kk] * wval;
    }
  } else {
    int cc = c - 192;
    #pragma unroll
    for (int t = 0; t < TM; t++) acc[t] = bph[cc];
    for (int kk = 0; kk < ACH; kk++) {
      float wval = wph[(size_t)kk * ACH + cc];
      #pragma unroll
      for (int t = 0; t < TM; t++) acc[t] += rh[t][kk] * wval;
    }
  }
  #pragma unroll
  for (int t = 0; t < TM; t++) {
    size_t idx = (size_t)(t0 + t) * CDIM + c;
    x2[idx] = x[idx] + acc[t];
  }
}

// ------------- LN2 + MLP (fc1 → exact GELU → fc2) + residual, in-place -------------
__global__ __launch_bounds__(256) void mlp_kernel(
    float* __restrict__ xio,
    const float* __restrict__ lw, const float* __restrict__ lb,
    const float* __restrict__ w1, const float* __restrict__ b1,
    const float* __restrict__ w2, const float* __restrict__ b2)
{
  constexpr int TM = 4;
  __shared__ float nrow[TM][CDIM];
  __shared__ float hid[TM][1024];
  __shared__ float red[8][TM];
  int t0 = blockIdx.x * TM;
  int c = threadIdx.x;
  int lane = c & 63, wvid = c >> 6;
  float xv[TM];
  #pragma unroll
  for (int t = 0; t < TM; t++) xv[t] = xio[(size_t)(t0 + t) * CDIM + c];
  float s[TM], s2[TM];
  #pragma unroll
  for (int t = 0; t < TM; t++) { s[t] = xv[t]; s2[t] = xv[t] * xv[t]; }
  #pragma unroll
  for (int o = 32; o; o >>= 1) {
    #pragma unroll
    for (int t = 0; t < TM; t++) { s[t] += __shfl_xor(s[t], o); s2[t] += __shfl_xor(s2[t], o); }
  }
  if (lane == 0) {
    #pragma unroll
    for (int t = 0; t < TM; t++) { red[wvid][t] = s[t]; red[4 + wvid][t] = s2[t]; }
  }
  __syncthreads();
  #pragma unroll
  for (int t = 0; t < TM; t++) {
    float a  = red[0][t] + red[1][t] + red[2][t] + red[3][t];
    float a2 = red[4][t] + red[5][t] + red[6][t] + red[7][t];
    float mu  = a * (1.f / CDIM);
    float var = a2 * (1.f / CDIM) - mu * mu;
    float rs  = rsqrtf(var + 1e-5f);
    nrow[t][c] = (xv[t] - mu) * rs * lw[c] + lb[c];
  }
  __syncthreads();
  #pragma unroll
  for (int g = 0; g < 4; g++) {
    int hh = c + g * 256;
    float acc[TM];
    #pragma unroll
    for (int t = 0; t < TM; t++) acc[t] = b1[hh];
    for (int k = 0; k < CDIM; k++) {
      float wval = w1[(size_t)k * 1024 + hh];
      #pragma unroll
      for (int t = 0; t < TM; t++) acc[t] += nrow[t][k] * wval;
    }
    #pragma unroll
    for (int t = 0; t < TM; t++) {
      float hv = acc[t];
      hid[t][hh] = 0.5f * hv * (1.f + erff(hv * 0.70710678118654752f));
    }
  }
  __syncthreads();
  float acc2[TM];
  #pragma unroll
  for (int t = 0; t < TM; t++) acc2[t] = b2[c];
  for (int k = 0; k < 1024; k++) {
    float wval = w2[(size_t)k * CDIM + c];
    #pragma unroll
    for (int t = 0; t < TM; t++) acc2[t] += hid[t][k] * wval;
  }
  #pragma unroll
  for (int t = 0; t < TM; t++) {
    size_t idx = (size_t)(t0 + t) * CDIM + c;
    xio[idx] = xv[t] + acc2[t];
  }
}

}  // namespace

extern "C" void kernel_launch(void* const* d_in, const int* in_sizes, int n_in,
                              void* d_out, int out_size, void* d_ws, size_t ws_size,
                              hipStream_t stream)
{
  const float* x    = (const float*)d_in[0];
  // d_in[1]=H, d_in[2]=W (constants 112, unused)
  const float* ln1w = (const float*)d_in[3];
  const float* ln1b = (const float*)d_in[4];
  const float* ln2w = (const float*)d_in[5];
  const float* ln2b = (const float*)d_in[6];
  const float* btbl = (const float*)d_in[7];
  const float* lwq  = (const float*)d_in[8];
  const float* lbq  = (const float*)d_in[9];
  const float* lwk  = (const float*)d_in[10];
  const float* lbk  = (const float*)d_in[11];
  const float* lwv  = (const float*)d_in[12];
  const float* lbv  = (const float*)d_in[13];
  const float* lwp  = (const float*)d_in[14];
  const float* lbp  = (const float*)d_in[15];
  const float* vwq  = (const float*)d_in[16];
  const float* vbq  = (const float*)d_in[17];
  const float* vwk  = (const float*)d_in[18];
  const float* vbk  = (const float*)d_in[19];
  const float* vwv  = (const float*)d_in[20];
  const float* vbv  = (const float*)d_in[21];
  const float* vwp  = (const float*)d_in[22];
  const float* vbp  = (const float*)d_in[23];
  const float* hwq  = (const float*)d_in[24];
  const float* hbq  = (const float*)d_in[25];
  const float* hwk  = (const float*)d_in[26];
  const float* hbk  = (const float*)d_in[27];
  const float* hwv  = (const float*)d_in[28];
  const float* hbv  = (const float*)d_in[29];
  const float* hwp  = (const float*)d_in[30];
  const float* hbp  = (const float*)d_in[31];
  const float* fc1w = (const float*)d_in[32];
  const float* fc1b = (const float*)d_in[33];
  const float* fc2w = (const float*)d_in[34];
  const float* fc2b = (const float*)d_in[35];

  float* ws = (float*)d_ws;
  size_t off = 0;
  auto alloc = [&](size_t n) { float* p = ws + off; off += n; return p; };
  float* h1  = alloc((size_t)NTOK * CDIM);   // ln1 output
  float* ql  = alloc((size_t)NTOK * LCH);
  float* klb = alloc((size_t)NTOK * LCH);
  float* vlb = alloc((size_t)NTOK * LCH);
  float* olb = alloc((size_t)NTOK * LCH);
  float* qv  = alloc((size_t)NTOK * ACH);
  float* kvb = alloc((size_t)NTOK * ACH);
  float* vvb = alloc((size_t)NTOK * ACH);
  float* ovb = alloc((size_t)NTOK * ACH);
  float* qh  = alloc((size_t)NTOK * ACH);
  float* khb = alloc((size_t)NTOK * ACH);
  float* vhb = alloc((size_t)NTOK * ACH);
  float* ohb = alloc((size_t)NTOK * ACH);
  float* x2  = (float*)d_out;                // x2 lives in d_out; mlp runs in-place

  ln1_kernel<<<NTOK, 256, 0, stream>>>(x, ln1w, ln1b, h1);
  qkv_kernel<128><<<NTOK / 4, 256, 0, stream>>>(h1, 0,   lwq, lbq, lwk, lbk, lwv, lbv,
                                                ql, klb, vlb, QSC);
  qkv_kernel<64><<<NTOK / 4, 256, 0, stream>>>(h1, 128, vwq, vbq, vwk, vbk, vwv, vbv,
                                               qv, kvb, vvb, QSC);
  qkv_kernel<64><<<NTOK / 4, 256, 0, stream>>>(h1, 192, hwq, hbq, hwk, hbk, hwv, hbv,
                                               qh, khb, vhb, QSC);
  loc_attn_kernel<<<4096, 256, 0, stream>>>(ql, klb, vlb, lbk, lbv, btbl, olb);
  axial_attn_kernel<<<896, 256, 0, stream>>>(qv, kvb, vvb, ovb, 1);
  axial_attn_kernel<<<896, 256, 0, stream>>>(qh, khb, vhb, ohb, 0);
  proj_res_kernel<<<NTOK / 4, 256, 0, stream>>>(x, olb, ovb, ohb,
                                                lwp, lbp, vwp, vbp, hwp, hbp, x2);
  mlp_kernel<<<NTOK / 4, 256, 0, stream>>>(x2, ln2w, ln2b, fc1w, fc1b, fc2w, fc2b);
}

// Round 2
// 2985.099 us; speedup vs baseline: 1.8452x; 1.8452x over previous
//
#include <hip/hip_runtime.h>
#include <math.h>

// MixAxialPOLABlock — round 2: MFMA bf16 local-window attention.
// B=4, H=W=112, C=256 = [local 128 | vert-axial 64 | horz-axial 64]

namespace {

constexpr int IMG  = 112;
constexpr int NTOK = 4 * IMG * IMG;   // 50176
constexpr int CDIM = 256;
constexpr int LCH  = 128;
constexpr int ACH  = 64;
constexpr float QSC = 0.17677669529663687f;  // 1/sqrt(32)

typedef __attribute__((ext_vector_type(8))) short bf16x8;
typedef __attribute__((ext_vector_type(4))) float f32x4;

__device__ inline short f2bf(float f) {
  union { float f; unsigned u; } c; c.f = f;
  unsigned u = c.u;
  return (short)((u + 0x7fffu + ((u >> 16) & 1u)) >> 16);
}

// ---------------- LayerNorm (ln1) : one block per token ----------------
__global__ __launch_bounds__(256) void ln1_kernel(
    const float* __restrict__ x, const float* __restrict__ w,
    const float* __restrict__ b, float* __restrict__ out)
{
  int tok = blockIdx.x;
  int c = threadIdx.x;
  size_t idx = (size_t)tok * CDIM + c;
  float v = x[idx];
  float s = v, s2 = v * v;
  #pragma unroll
  for (int o = 32; o; o >>= 1) { s += __shfl_xor(s, o); s2 += __shfl_xor(s2, o); }
  __shared__ float red[8];
  int lane = c & 63, wv = c >> 6;
  if (lane == 0) { red[wv] = s; red[4 + wv] = s2; }
  __syncthreads();
  float a  = red[0] + red[1] + red[2] + red[3];
  float a2 = red[4] + red[5] + red[6] + red[7];
  float mu  = a * (1.f / CDIM);
  float var = a2 * (1.f / CDIM) - mu * mu;
  float rs  = rsqrtf(var + 1e-5f);
  out[idx] = (v - mu) * rs * w[c] + b[c];
}

// ------------- fused q/k/v projection for one channel group -------------
template<int IN>
__global__ __launch_bounds__(256) void qkv_kernel(
    const float* __restrict__ h1, int in_off,
    const float* __restrict__ wq, const float* __restrict__ bq,
    const float* __restrict__ wk, const float* __restrict__ bk,
    const float* __restrict__ wv, const float* __restrict__ bv,
    float* __restrict__ qo, float* __restrict__ ko, float* __restrict__ vo,
    float qscale)
{
  constexpr int TM = 4;
  __shared__ float rows[TM][IN];
  int t0 = blockIdx.x * TM;
  for (int i = threadIdx.x; i < TM * IN; i += 256) {
    int t = i / IN, k = i % IN;
    rows[t][k] = h1[(size_t)(t0 + t) * CDIM + in_off + k];
  }
  __syncthreads();
  for (int o = threadIdx.x; o < 3 * IN; o += 256) {
    int sel = o / IN, col = o % IN;
    const float* wm = sel == 0 ? wq : (sel == 1 ? wk : wv);
    const float* bm = sel == 0 ? bq : (sel == 1 ? bk : bv);
    float sc = (sel == 0) ? qscale : 1.0f;
    float acc[TM];
    #pragma unroll
    for (int t = 0; t < TM; t++) acc[t] = 0.f;
    for (int k = 0; k < IN; k++) {
      float wval = wm[(size_t)k * IN + col];
      #pragma unroll
      for (int t = 0; t < TM; t++) acc[t] += rows[t][k] * wval;
    }
    float* op = sel == 0 ? qo : (sel == 1 ? ko : vo);
    #pragma unroll
    for (int t = 0; t < TM; t++)
      op[(size_t)(t0 + t) * IN + col] = (acc[t] + bm[col]) * sc;
  }
}

// ---------------- local window attention, MFMA bf16 ----------------
// block = (window, head), 4 waves; wave w owns query rows 16w..16w+15 (49 real).
// Two passes: S = Q·K^T (K in LDS row-major), softmax in regs,
// O = P·V (V^T in LDS, P round-trips via wave-private LDS chunk).
__global__ __launch_bounds__(256) void loc_attn_mfma(
    const float* __restrict__ ql, const float* __restrict__ kl,
    const float* __restrict__ vl, const float* __restrict__ bk,
    const float* __restrict__ bv, const float* __restrict__ btbl,
    float* __restrict__ ol)
{
  constexpr int KSTR = 40;    // K row stride (bf16): 16B-aligned, 2-way banks (free)
  constexpr int VSTR = 456;   // V^T row stride (bf16): 912B, 16B-aligned, 2-way
  constexpr int PSTR = 40;    // P chunk row stride
  __shared__ short kv_lds[448 * KSTR];          // K rows; later V^T (32 x VSTR <= same)
  __shared__ float bias_lds[736];               // 729 used
  __shared__ short p_lds[4][16 * PSTR];         // per-wave P chunk (16 x 32)

  int head = blockIdx.x & 3;
  int wi = blockIdx.x >> 2;
  int wx = wi & 15, wy = (wi >> 4) & 15, b = wi >> 8;
  int tid = threadIdx.x;
  int lane = tid & 63, wv = tid >> 6;
  int g = lane >> 4, l15 = lane & 15;
  const float* bkh = bk + head * 32;
  const float* bvh = bv + head * 32;

  // ---- stage K (bf16, row-major) + bias head-slice ----
  for (int it = tid; it < 448 * 4; it += 256) {
    int key = it >> 2, dg = it & 3;
    float buf[8];
    if (key < 441) {
      int ky = key / 21, kx = key - ky * 21;
      int rr = wy * 7 + ky - 7, cc = wx * 7 + kx - 7;
      const float* src;
      if ((unsigned)rr < (unsigned)IMG && (unsigned)cc < (unsigned)IMG)
        src = kl + ((size_t)((b * IMG + rr) * IMG + cc)) * LCH + head * 32 + dg * 8;
      else
        src = bkh + dg * 8;
      float4 a0 = *(const float4*)src;
      float4 a1 = *(const float4*)(src + 4);
      buf[0] = a0.x; buf[1] = a0.y; buf[2] = a0.z; buf[3] = a0.w;
      buf[4] = a1.x; buf[5] = a1.y; buf[6] = a1.z; buf[7] = a1.w;
    } else {
      #pragma unroll
      for (int j = 0; j < 8; j++) buf[j] = 0.f;
    }
    bf16x8 f;
    #pragma unroll
    for (int j = 0; j < 8; j++) f[j] = f2bf(buf[j]);
    *(bf16x8*)(&kv_lds[key * KSTR + dg * 8]) = f;
  }
  for (int i = tid; i < 729; i += 256) bias_lds[i] = btbl[i * 4 + head];

  // ---- Q A-fragment (global, fp32 -> bf16): A[m=l15][k=g*8+j] ----
  int q0 = wv * 16 + l15;
  int qc = q0 < 49 ? q0 : 48;
  int qy0 = qc / 7, qx0 = qc - qy0 * 7;
  size_t qbase = ((size_t)((b * IMG + wy * 7 + qy0) * IMG + wx * 7 + qx0)) * LCH
                 + head * 32 + g * 8;
  float4 qa = *(const float4*)(ql + qbase);
  float4 qb = *(const float4*)(ql + qbase + 4);
  bf16x8 qfrag;
  qfrag[0] = f2bf(qa.x); qfrag[1] = f2bf(qa.y); qfrag[2] = f2bf(qa.z); qfrag[3] = f2bf(qa.w);
  qfrag[4] = f2bf(qb.x); qfrag[5] = f2bf(qb.y); qfrag[6] = f2bf(qb.z); qfrag[7] = f2bf(qb.w);

  __syncthreads();

  // ---- S = Q·K^T : 28 N-tiles, acc[n] C-layout col=l15, row=4g+r ----
  f32x4 acc[28];
  #pragma unroll
  for (int n = 0; n < 28; n++) {
    bf16x8 kfrag = *(bf16x8*)(&kv_lds[(n * 16 + l15) * KSTR + g * 8]);
    f32x4 z = {0.f, 0.f, 0.f, 0.f};
    acc[n] = __builtin_amdgcn_mfma_f32_16x16x32_bf16(qfrag, kfrag, z, 0, 0, 0);
  }

  // ---- bias + softmax (registers; row reduce over 16-lane col group) ----
  float rinv[4];
  #pragma unroll
  for (int r = 0; r < 4; r++) {
    int q = wv * 16 + g * 4 + r;
    int qq = q < 49 ? q : 0;
    int qy = qq / 7, qx = qq - qy * 7;
    float m = -1e30f;
    #pragma unroll
    for (int n = 0; n < 28; n++) {
      int key = n * 16 + l15;
      if (key < 441) {
        int ky = key / 21, kx = key - ky * 21;
        float s = acc[n][r] + bias_lds[(qy - ky + 20) * 27 + (qx - kx + 20)];
        acc[n][r] = s;
        m = fmaxf(m, s);
      } else {
        acc[n][r] = -1e30f;
      }
    }
    m = fmaxf(m, __shfl_xor(m, 1));
    m = fmaxf(m, __shfl_xor(m, 2));
    m = fmaxf(m, __shfl_xor(m, 4));
    m = fmaxf(m, __shfl_xor(m, 8));
    float sum = 0.f;
    #pragma unroll
    for (int n = 0; n < 28; n++) {
      float p = (acc[n][r] > -1e29f) ? __expf(acc[n][r] - m) : 0.f;
      acc[n][r] = p;
      sum += p;
    }
    sum += __shfl_xor(sum, 1);
    sum += __shfl_xor(sum, 2);
    sum += __shfl_xor(sum, 4);
    sum += __shfl_xor(sum, 8);
    rinv[r] = 1.f / sum;
  }

  __syncthreads();   // all waves done reading K region

  // ---- stage V^T (bf16) into kv_lds: VT[d][key], stride VSTR ----
  for (int it = tid; it < 448 * 4; it += 256) {
    int key = it >> 2, dg = it & 3;
    float buf[8];
    if (key < 441) {
      int ky = key / 21, kx = key - ky * 21;
      int rr = wy * 7 + ky - 7, cc = wx * 7 + kx - 7;
      const float* src;
      if ((unsigned)rr < (unsigned)IMG && (unsigned)cc < (unsigned)IMG)
        src = vl + ((size_t)((b * IMG + rr) * IMG + cc)) * LCH + head * 32 + dg * 8;
      else
        src = bvh + dg * 8;
      float4 a0 = *(const float4*)src;
      float4 a1 = *(const float4*)(src + 4);
      buf[0] = a0.x; buf[1] = a0.y; buf[2] = a0.z; buf[3] = a0.w;
      buf[4] = a1.x; buf[5] = a1.y; buf[6] = a1.z; buf[7] = a1.w;
    } else {
      #pragma unroll
      for (int j = 0; j < 8; j++) buf[j] = 0.f;
    }
    #pragma unroll
    for (int j = 0; j < 8; j++) kv_lds[(dg * 8 + j) * VSTR + key] = f2bf(buf[j]);
  }
  __syncthreads();

  // ---- O = P·V : 14 K-chunks of 32 keys; P via wave-private LDS chunk ----
  f32x4 oacc[2];
  oacc[0] = (f32x4){0.f, 0.f, 0.f, 0.f};
  oacc[1] = (f32x4){0.f, 0.f, 0.f, 0.f};
  short* pw = p_lds[wv];
  #pragma unroll 1
  for (int c = 0; c < 14; c++) {
    #pragma unroll
    for (int t = 0; t < 2; t++) {
      int n = 2 * c + t;
      #pragma unroll
      for (int r = 0; r < 4; r++) {
        float pv0 = ((&acc[0])[n])[r];
        pw[(g * 4 + r) * PSTR + t * 16 + l15] = f2bf(pv0);
      }
    }
    asm volatile("s_waitcnt lgkmcnt(0)" ::: "memory");
    bf16x8 pfrag = *(bf16x8*)(&pw[l15 * PSTR + g * 8]);
    #pragma unroll
    for (int nt = 0; nt < 2; nt++) {
      bf16x8 vfrag = *(bf16x8*)(&kv_lds[(nt * 16 + l15) * VSTR + c * 32 + g * 8]);
      oacc[nt] = __builtin_amdgcn_mfma_f32_16x16x32_bf16(pfrag, vfrag, oacc[nt], 0, 0, 0);
    }
  }

  // ---- store O (fold 1/sum here), rows < 49 only ----
  #pragma unroll
  for (int r = 0; r < 4; r++) {
    int q = wv * 16 + g * 4 + r;
    if (q < 49) {
      int qy = q / 7, qx = q - qy * 7;
      size_t obase = ((size_t)((b * IMG + wy * 7 + qy) * IMG + wx * 7 + qx)) * LCH
                     + head * 32;
      ol[obase + l15]      = oacc[0][r] * rinv[r];
      ol[obase + 16 + l15] = oacc[1][r] * rinv[r];
    }
  }
}

// ---------------- axial attention (vert: over h; horz: over w) ----------------
__global__ __launch_bounds__(256) void axial_attn_kernel(
    const float* __restrict__ q, const float* __restrict__ k,
    const float* __restrict__ v, float* __restrict__ out, int vert)
{
  int head = blockIdx.x & 1;
  int s = blockIdx.x >> 1;
  int b = s / IMG, t = s % IMG;
  size_t base; int stride;
  if (vert) { base = ((size_t)b * IMG * IMG + t) * ACH; stride = IMG * ACH; }
  else      { base = ((size_t)(b * IMG + t)) * (size_t)IMG * ACH; stride = ACH; }
  base += head * 32;
  int lane = threadIdx.x & 63, wvid = threadIdx.x >> 6;
  __shared__ float qs[4][32];
  __shared__ float probs[4][112];

  for (int qi = wvid; qi < IMG; qi += 4) {
    __syncthreads();
    if (lane < 32) qs[wvid][lane] = q[base + (size_t)qi * stride + lane];
    __syncthreads();
    float qreg[32];
    #pragma unroll
    for (int d = 0; d < 32; d++) qreg[d] = qs[wvid][d];
    float lg[2];
    float m = -1e30f;
    #pragma unroll
    for (int jj = 0; jj < 2; jj++) {
      int j = jj * 64 + lane;
      if (j < IMG) {
        const float* kp = k + base + (size_t)j * stride;
        float acc = 0.f;
        #pragma unroll
        for (int d = 0; d < 32; d++) acc += qreg[d] * kp[d];
        lg[jj] = acc;
        m = fmaxf(m, acc);
      }
    }
    #pragma unroll
    for (int o = 32; o; o >>= 1) m = fmaxf(m, __shfl_xor(m, o));
    float ssum = 0.f;
    #pragma unroll
    for (int jj = 0; jj < 2; jj++) {
      int j = jj * 64 + lane;
      if (j < IMG) {
        float p = __expf(lg[jj] - m);
        probs[wvid][j] = p;
        ssum += p;
      }
    }
    #pragma unroll
    for (int o = 32; o; o >>= 1) ssum += __shfl_xor(ssum, o);
    float inv = 1.f / ssum;
    __syncthreads();
    int d = lane & 31, half = lane >> 5;
    float acc = 0.f;
    for (int j = half; j < IMG; j += 2)
      acc += probs[wvid][j] * v[base + (size_t)j * stride + d];
    acc += __shfl_xor(acc, 32);
    if (half == 0) out[base + (size_t)qi * stride + d] = acc * inv;
  }
}

// ------------- output projections + residual concat → x2 (in d_out) -------------
__global__ __launch_bounds__(256) void proj_res_kernel(
    const float* __restrict__ x, const float* __restrict__ ol,
    const float* __restrict__ ov, const float* __restrict__ oh,
    const float* __restrict__ wpl, const float* __restrict__ bpl,
    const float* __restrict__ wpv, const float* __restrict__ bpv,
    const float* __restrict__ wph, const float* __restrict__ bph,
    float* __restrict__ x2)
{
  constexpr int TM = 4;
  __shared__ float rl[TM][LCH];
  __shared__ float rv[TM][ACH];
  __shared__ float rh[TM][ACH];
  int t0 = blockIdx.x * TM;
  for (int i = threadIdx.x; i < TM * LCH; i += 256) {
    int t = i >> 7, c = i & 127;
    rl[t][c] = ol[(size_t)(t0 + t) * LCH + c];
  }
  for (int i = threadIdx.x; i < TM * ACH; i += 256) {
    int t = i >> 6, c = i & 63;
    rv[t][c] = ov[(size_t)(t0 + t) * ACH + c];
    rh[t][c] = oh[(size_t)(t0 + t) * ACH + c];
  }
  __syncthreads();
  int c = threadIdx.x;
  float acc[TM];
  if (c < 128) {
    #pragma unroll
    for (int t = 0; t < TM; t++) acc[t] = bpl[c];
    for (int kk = 0; kk < LCH; kk++) {
      float wval = wpl[(size_t)kk * LCH + c];
      #pragma unroll
      for (int t = 0; t < TM; t++) acc[t] += rl[t][kk] * wval;
    }
  } else if (c < 192) {
    int cc = c - 128;
    #pragma unroll
    for (int t = 0; t < TM; t++) acc[t] = bpv[cc];
    for (int kk = 0; kk < ACH; kk++) {
      float wval = wpv[(size_t)kk * ACH + cc];
      #pragma unroll
      for (int t = 0; t < TM; t++) acc[t] += rv[t][kk] * wval;
    }
  } else {
    int cc = c - 192;
    #pragma unroll
    for (int t = 0; t < TM; t++) acc[t] = bph[cc];
    for (int kk = 0; kk < ACH; kk++) {
      float wval = wph[(size_t)kk * ACH + cc];
      #pragma unroll
      for (int t = 0; t < TM; t++) acc[t] += rh[t][kk] * wval;
    }
  }
  #pragma unroll
  for (int t = 0; t < TM; t++) {
    size_t idx = (size_t)(t0 + t) * CDIM + c;
    x2[idx] = x[idx] + acc[t];
  }
}

// ------------- LN2 + MLP (fc1 → exact GELU → fc2) + residual, in-place -------------
__global__ __launch_bounds__(256) void mlp_kernel(
    float* __restrict__ xio,
    const float* __restrict__ lw, const float* __restrict__ lb,
    const float* __restrict__ w1, const float* __restrict__ b1,
    const float* __restrict__ w2, const float* __restrict__ b2)
{
  constexpr int TM = 4;
  __shared__ float nrow[TM][CDIM];
  __shared__ float hid[TM][1024];
  __shared__ float red[8][TM];
  int t0 = blockIdx.x * TM;
  int c = threadIdx.x;
  int lane = c & 63, wvid = c >> 6;
  float xv[TM];
  #pragma unroll
  for (int t = 0; t < TM; t++) xv[t] = xio[(size_t)(t0 + t) * CDIM + c];
  float s[TM], s2[TM];
  #pragma unroll
  for (int t = 0; t < TM; t++) { s[t] = xv[t]; s2[t] = xv[t] * xv[t]; }
  #pragma unroll
  for (int o = 32; o; o >>= 1) {
    #pragma unroll
    for (int t = 0; t < TM; t++) { s[t] += __shfl_xor(s[t], o); s2[t] += __shfl_xor(s2[t], o); }
  }
  if (lane == 0) {
    #pragma unroll
    for (int t = 0; t < TM; t++) { red[wvid][t] = s[t]; red[4 + wvid][t] = s2[t]; }
  }
  __syncthreads();
  #pragma unroll
  for (int t = 0; t < TM; t++) {
    float a  = red[0][t] + red[1][t] + red[2][t] + red[3][t];
    float a2 = red[4][t] + red[5][t] + red[6][t] + red[7][t];
    float mu  = a * (1.f / CDIM);
    float var = a2 * (1.f / CDIM) - mu * mu;
    float rs  = rsqrtf(var + 1e-5f);
    nrow[t][c] = (xv[t] - mu) * rs * lw[c] + lb[c];
  }
  __syncthreads();
  #pragma unroll
  for (int gq = 0; gq < 4; gq++) {
    int hh = c + gq * 256;
    float acc[TM];
    #pragma unroll
    for (int t = 0; t < TM; t++) acc[t] = b1[hh];
    for (int k = 0; k < CDIM; k++) {
      float wval = w1[(size_t)k * 1024 + hh];
      #pragma unroll
      for (int t = 0; t < TM; t++) acc[t] += nrow[t][k] * wval;
    }
    #pragma unroll
    for (int t = 0; t < TM; t++) {
      float hv = acc[t];
      hid[t][hh] = 0.5f * hv * (1.f + erff(hv * 0.70710678118654752f));
    }
  }
  __syncthreads();
  float acc2[TM];
  #pragma unroll
  for (int t = 0; t < TM; t++) acc2[t] = b2[c];
  for (int k = 0; k < 1024; k++) {
    float wval = w2[(size_t)k * CDIM + c];
    #pragma unroll
    for (int t = 0; t < TM; t++) acc2[t] += hid[t][k] * wval;
  }
  #pragma unroll
  for (int t = 0; t < TM; t++) {
    size_t idx = (size_t)(t0 + t) * CDIM + c;
    xio[idx] = xv[t] + acc2[t];
  }
}

}  // namespace

extern "C" void kernel_launch(void* const* d_in, const int* in_sizes, int n_in,
                              void* d_out, int out_size, void* d_ws, size_t ws_size,
                              hipStream_t stream)
{
  const float* x    = (const float*)d_in[0];
  const float* ln1w = (const float*)d_in[3];
  const float* ln1b = (const float*)d_in[4];
  const float* ln2w = (const float*)d_in[5];
  const float* ln2b = (const float*)d_in[6];
  const float* btbl = (const float*)d_in[7];
  const float* lwq  = (const float*)d_in[8];
  const float* lbq  = (const float*)d_in[9];
  const float* lwk  = (const float*)d_in[10];
  const float* lbk  = (const float*)d_in[11];
  const float* lwv  = (const float*)d_in[12];
  const float* lbv  = (const float*)d_in[13];
  const float* lwp  = (const float*)d_in[14];
  const float* lbp  = (const float*)d_in[15];
  const float* vwq  = (const float*)d_in[16];
  const float* vbq  = (const float*)d_in[17];
  const float* vwk  = (const float*)d_in[18];
  const float* vbk  = (const float*)d_in[19];
  const float* vwv  = (const float*)d_in[20];
  const float* vbv  = (const float*)d_in[21];
  const float* vwp  = (const float*)d_in[22];
  const float* vbp  = (const float*)d_in[23];
  const float* hwq  = (const float*)d_in[24];
  const float* hbq  = (const float*)d_in[25];
  const float* hwk  = (const float*)d_in[26];
  const float* hbk  = (const float*)d_in[27];
  const float* hwv  = (const float*)d_in[28];
  const float* hbv  = (const float*)d_in[29];
  const float* hwp  = (const float*)d_in[30];
  const float* hbp  = (const float*)d_in[31];
  const float* fc1w = (const float*)d_in[32];
  const float* fc1b = (const float*)d_in[33];
  const float* fc2w = (const float*)d_in[34];
  const float* fc2b = (const float*)d_in[35];

  float* ws = (float*)d_ws;
  size_t off = 0;
  auto alloc = [&](size_t n) { float* p = ws + off; off += n; return p; };
  float* h1  = alloc((size_t)NTOK * CDIM);
  float* ql  = alloc((size_t)NTOK * LCH);
  float* klb = alloc((size_t)NTOK * LCH);
  float* vlb = alloc((size_t)NTOK * LCH);
  float* olb = alloc((size_t)NTOK * LCH);
  float* qv  = alloc((size_t)NTOK * ACH);
  float* kvb = alloc((size_t)NTOK * ACH);
  float* vvb = alloc((size_t)NTOK * ACH);
  float* ovb = alloc((size_t)NTOK * ACH);
  float* qh  = alloc((size_t)NTOK * ACH);
  float* khb = alloc((size_t)NTOK * ACH);
  float* vhb = alloc((size_t)NTOK * ACH);
  float* ohb = alloc((size_t)NTOK * ACH);
  float* x2  = (float*)d_out;

  ln1_kernel<<<NTOK, 256, 0, stream>>>(x, ln1w, ln1b, h1);
  qkv_kernel<128><<<NTOK / 4, 256, 0, stream>>>(h1, 0,   lwq, lbq, lwk, lbk, lwv, lbv,
                                                ql, klb, vlb, QSC);
  qkv_kernel<64><<<NTOK / 4, 256, 0, stream>>>(h1, 128, vwq, vbq, vwk, vbk, vwv, vbv,
                                               qv, kvb, vvb, QSC);
  qkv_kernel<64><<<NTOK / 4, 256, 0, stream>>>(h1, 192, hwq, hbq, hwk, hbk, hwv, hbv,
                                               qh, khb, vhb, QSC);
  loc_attn_mfma<<<4096, 256, 0, stream>>>(ql, klb, vlb, lbk, lbv, btbl, olb);
  axial_attn_kernel<<<896, 256, 0, stream>>>(qv, kvb, vvb, ovb, 1);
  axial_attn_kernel<<<896, 256, 0, stream>>>(qh, khb, vhb, ohb, 0);
  proj_res_kernel<<<NTOK / 4, 256, 0, stream>>>(x, olb, ovb, ohb,
                                                lwp, lbp, vwp, vbp, hwp, hbp, x2);
  mlp_kernel<<<NTOK / 4, 256, 0, stream>>>(x2, ln2w, ln2b, fc1w, fc1b, fc2w, fc2b);
}

// Round 3
// 1843.175 us; speedup vs baseline: 2.9885x; 1.6195x over previous
//
#include <hip/hip_runtime.h>
#include <math.h>

// MixAxialPOLABlock — round 3: MFMA bf16 MLP (gemm1+GELU, gemm2+residual),
// LN2 fused into proj_res epilogue. Local attention already MFMA (round 2).

namespace {

constexpr int IMG  = 112;
constexpr int NTOK = 4 * IMG * IMG;   // 50176
constexpr int CDIM = 256;
constexpr int LCH  = 128;
constexpr int ACH  = 64;
constexpr int HID  = 1024;
constexpr float QSC = 0.17677669529663687f;  // 1/sqrt(32)

typedef __attribute__((ext_vector_type(8))) short bf16x8;
typedef __attribute__((ext_vector_type(4))) float f32x4;

__device__ inline short f2bf(float f) {
  union { float f; unsigned u; } c; c.f = f;
  unsigned u = c.u;
  return (short)((u + 0x7fffu + ((u >> 16) & 1u)) >> 16);
}

// ---------------- weight transpose + bf16 convert: src[K][N] -> dst[N][K] ----------------
__global__ __launch_bounds__(256) void conv_w_kernel(
    const float* __restrict__ src, short* __restrict__ dst, int K, int N)
{
  int idx = blockIdx.x * 256 + threadIdx.x;
  if (idx < K * N) {
    int n = idx / K, k = idx - n * K;
    dst[idx] = f2bf(src[(size_t)k * N + n]);
  }
}

// ---------------- LayerNorm (ln1) : one block per token ----------------
__global__ __launch_bounds__(256) void ln1_kernel(
    const float* __restrict__ x, const float* __restrict__ w,
    const float* __restrict__ b, float* __restrict__ out)
{
  int tok = blockIdx.x;
  int c = threadIdx.x;
  size_t idx = (size_t)tok * CDIM + c;
  float v = x[idx];
  float s = v, s2 = v * v;
  #pragma unroll
  for (int o = 32; o; o >>= 1) { s += __shfl_xor(s, o); s2 += __shfl_xor(s2, o); }
  __shared__ float red[8];
  int lane = c & 63, wv = c >> 6;
  if (lane == 0) { red[wv] = s; red[4 + wv] = s2; }
  __syncthreads();
  float a  = red[0] + red[1] + red[2] + red[3];
  float a2 = red[4] + red[5] + red[6] + red[7];
  float mu  = a * (1.f / CDIM);
  float var = a2 * (1.f / CDIM) - mu * mu;
  float rs  = rsqrtf(var + 1e-5f);
  out[idx] = (v - mu) * rs * w[c] + b[c];
}

// ------------- fused q/k/v projection for one channel group -------------
template<int IN>
__global__ __launch_bounds__(256) void qkv_kernel(
    const float* __restrict__ h1, int in_off,
    const float* __restrict__ wq, const float* __restrict__ bq,
    const float* __restrict__ wk, const float* __restrict__ bk,
    const float* __restrict__ wv, const float* __restrict__ bv,
    float* __restrict__ qo, float* __restrict__ ko, float* __restrict__ vo,
    float qscale)
{
  constexpr int TM = 4;
  __shared__ float rows[TM][IN];
  int t0 = blockIdx.x * TM;
  for (int i = threadIdx.x; i < TM * IN; i += 256) {
    int t = i / IN, k = i % IN;
    rows[t][k] = h1[(size_t)(t0 + t) * CDIM + in_off + k];
  }
  __syncthreads();
  for (int o = threadIdx.x; o < 3 * IN; o += 256) {
    int sel = o / IN, col = o % IN;
    const float* wm = sel == 0 ? wq : (sel == 1 ? wk : wv);
    const float* bm = sel == 0 ? bq : (sel == 1 ? bk : bv);
    float sc = (sel == 0) ? qscale : 1.0f;
    float acc[TM];
    #pragma unroll
    for (int t = 0; t < TM; t++) acc[t] = 0.f;
    for (int k = 0; k < IN; k++) {
      float wval = wm[(size_t)k * IN + col];
      #pragma unroll
      for (int t = 0; t < TM; t++) acc[t] += rows[t][k] * wval;
    }
    float* op = sel == 0 ? qo : (sel == 1 ? ko : vo);
    #pragma unroll
    for (int t = 0; t < TM; t++)
      op[(size_t)(t0 + t) * IN + col] = (acc[t] + bm[col]) * sc;
  }
}

// ---------------- local window attention, MFMA bf16 ----------------
__global__ __launch_bounds__(256) void loc_attn_mfma(
    const float* __restrict__ ql, const float* __restrict__ kl,
    const float* __restrict__ vl, const float* __restrict__ bk,
    const float* __restrict__ bv, const float* __restrict__ btbl,
    float* __restrict__ ol)
{
  constexpr int KSTR = 40;
  constexpr int VSTR = 456;
  constexpr int PSTR = 40;
  __shared__ short kv_lds[448 * KSTR];
  __shared__ float bias_lds[736];
  __shared__ short p_lds[4][16 * PSTR];

  int head = blockIdx.x & 3;
  int wi = blockIdx.x >> 2;
  int wx = wi & 15, wy = (wi >> 4) & 15, b = wi >> 8;
  int tid = threadIdx.x;
  int lane = tid & 63, wv = tid >> 6;
  int g = lane >> 4, l15 = lane & 15;
  const float* bkh = bk + head * 32;
  const float* bvh = bv + head * 32;

  for (int it = tid; it < 448 * 4; it += 256) {
    int key = it >> 2, dg = it & 3;
    float buf[8];
    if (key < 441) {
      int ky = key / 21, kx = key - ky * 21;
      int rr = wy * 7 + ky - 7, cc = wx * 7 + kx - 7;
      const float* src;
      if ((unsigned)rr < (unsigned)IMG && (unsigned)cc < (unsigned)IMG)
        src = kl + ((size_t)((b * IMG + rr) * IMG + cc)) * LCH + head * 32 + dg * 8;
      else
        src = bkh + dg * 8;
      float4 a0 = *(const float4*)src;
      float4 a1 = *(const float4*)(src + 4);
      buf[0] = a0.x; buf[1] = a0.y; buf[2] = a0.z; buf[3] = a0.w;
      buf[4] = a1.x; buf[5] = a1.y; buf[6] = a1.z; buf[7] = a1.w;
    } else {
      #pragma unroll
      for (int j = 0; j < 8; j++) buf[j] = 0.f;
    }
    bf16x8 f;
    #pragma unroll
    for (int j = 0; j < 8; j++) f[j] = f2bf(buf[j]);
    *(bf16x8*)(&kv_lds[key * KSTR + dg * 8]) = f;
  }
  for (int i = tid; i < 729; i += 256) bias_lds[i] = btbl[i * 4 + head];

  int q0 = wv * 16 + l15;
  int qc = q0 < 49 ? q0 : 48;
  int qy0 = qc / 7, qx0 = qc - qy0 * 7;
  size_t qbase = ((size_t)((b * IMG + wy * 7 + qy0) * IMG + wx * 7 + qx0)) * LCH
                 + head * 32 + g * 8;
  float4 qa = *(const float4*)(ql + qbase);
  float4 qb = *(const float4*)(ql + qbase + 4);
  bf16x8 qfrag;
  qfrag[0] = f2bf(qa.x); qfrag[1] = f2bf(qa.y); qfrag[2] = f2bf(qa.z); qfrag[3] = f2bf(qa.w);
  qfrag[4] = f2bf(qb.x); qfrag[5] = f2bf(qb.y); qfrag[6] = f2bf(qb.z); qfrag[7] = f2bf(qb.w);

  __syncthreads();

  f32x4 acc[28];
  #pragma unroll
  for (int n = 0; n < 28; n++) {
    bf16x8 kfrag = *(bf16x8*)(&kv_lds[(n * 16 + l15) * KSTR + g * 8]);
    f32x4 z = {0.f, 0.f, 0.f, 0.f};
    acc[n] = __builtin_amdgcn_mfma_f32_16x16x32_bf16(qfrag, kfrag, z, 0, 0, 0);
  }

  float rinv[4];
  #pragma unroll
  for (int r = 0; r < 4; r++) {
    int q = wv * 16 + g * 4 + r;
    int qq = q < 49 ? q : 0;
    int qy = qq / 7, qx = qq - qy * 7;
    float m = -1e30f;
    #pragma unroll
    for (int n = 0; n < 28; n++) {
      int key = n * 16 + l15;
      if (key < 441) {
        int ky = key / 21, kx = key - ky * 21;
        float s = acc[n][r] + bias_lds[(qy - ky + 20) * 27 + (qx - kx + 20)];
        acc[n][r] = s;
        m = fmaxf(m, s);
      } else {
        acc[n][r] = -1e30f;
      }
    }
    m = fmaxf(m, __shfl_xor(m, 1));
    m = fmaxf(m, __shfl_xor(m, 2));
    m = fmaxf(m, __shfl_xor(m, 4));
    m = fmaxf(m, __shfl_xor(m, 8));
    float sum = 0.f;
    #pragma unroll
    for (int n = 0; n < 28; n++) {
      float p = (acc[n][r] > -1e29f) ? __expf(acc[n][r] - m) : 0.f;
      acc[n][r] = p;
      sum += p;
    }
    sum += __shfl_xor(sum, 1);
    sum += __shfl_xor(sum, 2);
    sum += __shfl_xor(sum, 4);
    sum += __shfl_xor(sum, 8);
    rinv[r] = 1.f / sum;
  }

  __syncthreads();

  for (int it = tid; it < 448 * 4; it += 256) {
    int key = it >> 2, dg = it & 3;
    float buf[8];
    if (key < 441) {
      int ky = key / 21, kx = key - ky * 21;
      int rr = wy * 7 + ky - 7, cc = wx * 7 + kx - 7;
      const float* src;
      if ((unsigned)rr < (unsigned)IMG && (unsigned)cc < (unsigned)IMG)
        src = vl + ((size_t)((b * IMG + rr) * IMG + cc)) * LCH + head * 32 + dg * 8;
      else
        src = bvh + dg * 8;
      float4 a0 = *(const float4*)src;
      float4 a1 = *(const float4*)(src + 4);
      buf[0] = a0.x; buf[1] = a0.y; buf[2] = a0.z; buf[3] = a0.w;
      buf[4] = a1.x; buf[5] = a1.y; buf[6] = a1.z; buf[7] = a1.w;
    } else {
      #pragma unroll
      for (int j = 0; j < 8; j++) buf[j] = 0.f;
    }
    #pragma unroll
    for (int j = 0; j < 8; j++) kv_lds[(dg * 8 + j) * VSTR + key] = f2bf(buf[j]);
  }
  __syncthreads();

  f32x4 oacc[2];
  oacc[0] = (f32x4){0.f, 0.f, 0.f, 0.f};
  oacc[1] = (f32x4){0.f, 0.f, 0.f, 0.f};
  short* pw = p_lds[wv];
  #pragma unroll 1
  for (int c = 0; c < 14; c++) {
    #pragma unroll
    for (int t = 0; t < 2; t++) {
      int n = 2 * c + t;
      #pragma unroll
      for (int r = 0; r < 4; r++) {
        float pv0 = ((&acc[0])[n])[r];
        pw[(g * 4 + r) * PSTR + t * 16 + l15] = f2bf(pv0);
      }
    }
    asm volatile("s_waitcnt lgkmcnt(0)" ::: "memory");
    bf16x8 pfrag = *(bf16x8*)(&pw[l15 * PSTR + g * 8]);
    #pragma unroll
    for (int nt = 0; nt < 2; nt++) {
      bf16x8 vfrag = *(bf16x8*)(&kv_lds[(nt * 16 + l15) * VSTR + c * 32 + g * 8]);
      oacc[nt] = __builtin_amdgcn_mfma_f32_16x16x32_bf16(pfrag, vfrag, oacc[nt], 0, 0, 0);
    }
  }

  #pragma unroll
  for (int r = 0; r < 4; r++) {
    int q = wv * 16 + g * 4 + r;
    if (q < 49) {
      int qy = q / 7, qx = q - qy * 7;
      size_t obase = ((size_t)((b * IMG + wy * 7 + qy) * IMG + wx * 7 + qx)) * LCH
                     + head * 32;
      ol[obase + l15]      = oacc[0][r] * rinv[r];
      ol[obase + 16 + l15] = oacc[1][r] * rinv[r];
    }
  }
}

// ---------------- axial attention (vert: over h; horz: over w) ----------------
__global__ __launch_bounds__(256) void axial_attn_kernel(
    const float* __restrict__ q, const float* __restrict__ k,
    const float* __restrict__ v, float* __restrict__ out, int vert)
{
  int head = blockIdx.x & 1;
  int s = blockIdx.x >> 1;
  int b = s / IMG, t = s % IMG;
  size_t base; int stride;
  if (vert) { base = ((size_t)b * IMG * IMG + t) * ACH; stride = IMG * ACH; }
  else      { base = ((size_t)(b * IMG + t)) * (size_t)IMG * ACH; stride = ACH; }
  base += head * 32;
  int lane = threadIdx.x & 63, wvid = threadIdx.x >> 6;
  __shared__ float qs[4][32];
  __shared__ float probs[4][112];

  for (int qi = wvid; qi < IMG; qi += 4) {
    __syncthreads();
    if (lane < 32) qs[wvid][lane] = q[base + (size_t)qi * stride + lane];
    __syncthreads();
    float qreg[32];
    #pragma unroll
    for (int d = 0; d < 32; d++) qreg[d] = qs[wvid][d];
    float lg[2];
    float m = -1e30f;
    #pragma unroll
    for (int jj = 0; jj < 2; jj++) {
      int j = jj * 64 + lane;
      if (j < IMG) {
        const float* kp = k + base + (size_t)j * stride;
        float acc = 0.f;
        #pragma unroll
        for (int d = 0; d < 32; d++) acc += qreg[d] * kp[d];
        lg[jj] = acc;
        m = fmaxf(m, acc);
      }
    }
    #pragma unroll
    for (int o = 32; o; o >>= 1) m = fmaxf(m, __shfl_xor(m, o));
    float ssum = 0.f;
    #pragma unroll
    for (int jj = 0; jj < 2; jj++) {
      int j = jj * 64 + lane;
      if (j < IMG) {
        float p = __expf(lg[jj] - m);
        probs[wvid][j] = p;
        ssum += p;
      }
    }
    #pragma unroll
    for (int o = 32; o; o >>= 1) ssum += __shfl_xor(ssum, o);
    float inv = 1.f / ssum;
    __syncthreads();
    int d = lane & 31, half = lane >> 5;
    float acc = 0.f;
    for (int j = half; j < IMG; j += 2)
      acc += probs[wvid][j] * v[base + (size_t)j * stride + d];
    acc += __shfl_xor(acc, 32);
    if (half == 0) out[base + (size_t)qi * stride + d] = acc * inv;
  }
}

// ------ output projections + residual concat → x2 (d_out) + fused LN2 → n2 bf16 ------
__global__ __launch_bounds__(256) void proj_res_ln2_kernel(
    const float* __restrict__ x, const float* __restrict__ ol,
    const float* __restrict__ ov, const float* __restrict__ oh,
    const float* __restrict__ wpl, const float* __restrict__ bpl,
    const float* __restrict__ wpv, const float* __restrict__ bpv,
    const float* __restrict__ wph, const float* __restrict__ bph,
    const float* __restrict__ lw, const float* __restrict__ lb,
    float* __restrict__ x2, short* __restrict__ n2)
{
  constexpr int TM = 4;
  __shared__ float rl[TM][LCH];
  __shared__ float rv[TM][ACH];
  __shared__ float rh[TM][ACH];
  __shared__ float red[8][TM];
  int t0 = blockIdx.x * TM;
  for (int i = threadIdx.x; i < TM * LCH; i += 256) {
    int t = i >> 7, c = i & 127;
    rl[t][c] = ol[(size_t)(t0 + t) * LCH + c];
  }
  for (int i = threadIdx.x; i < TM * ACH; i += 256) {
    int t = i >> 6, c = i & 63;
    rv[t][c] = ov[(size_t)(t0 + t) * ACH + c];
    rh[t][c] = oh[(size_t)(t0 + t) * ACH + c];
  }
  __syncthreads();
  int c = threadIdx.x;
  float acc[TM];
  if (c < 128) {
    #pragma unroll
    for (int t = 0; t < TM; t++) acc[t] = bpl[c];
    for (int kk = 0; kk < LCH; kk++) {
      float wval = wpl[(size_t)kk * LCH + c];
      #pragma unroll
      for (int t = 0; t < TM; t++) acc[t] += rl[t][kk] * wval;
    }
  } else if (c < 192) {
    int cc = c - 128;
    #pragma unroll
    for (int t = 0; t < TM; t++) acc[t] = bpv[cc];
    for (int kk = 0; kk < ACH; kk++) {
      float wval = wpv[(size_t)kk * ACH + cc];
      #pragma unroll
      for (int t = 0; t < TM; t++) acc[t] += rv[t][kk] * wval;
    }
  } else {
    int cc = c - 192;
    #pragma unroll
    for (int t = 0; t < TM; t++) acc[t] = bph[cc];
    for (int kk = 0; kk < ACH; kk++) {
      float wval = wph[(size_t)kk * ACH + cc];
      #pragma unroll
      for (int t = 0; t < TM; t++) acc[t] += rh[t][kk] * wval;
    }
  }
  float vals[TM];
  #pragma unroll
  for (int t = 0; t < TM; t++) {
    size_t idx = (size_t)(t0 + t) * CDIM + c;
    vals[t] = x[idx] + acc[t];
    x2[idx] = vals[t];
  }
  // fused LN2
  int lane = c & 63, wvid = c >> 6;
  float s[TM], s2[TM];
  #pragma unroll
  for (int t = 0; t < TM; t++) { s[t] = vals[t]; s2[t] = vals[t] * vals[t]; }
  #pragma unroll
  for (int o = 32; o; o >>= 1) {
    #pragma unroll
    for (int t = 0; t < TM; t++) { s[t] += __shfl_xor(s[t], o); s2[t] += __shfl_xor(s2[t], o); }
  }
  if (lane == 0) {
    #pragma unroll
    for (int t = 0; t < TM; t++) { red[wvid][t] = s[t]; red[4 + wvid][t] = s2[t]; }
  }
  __syncthreads();
  #pragma unroll
  for (int t = 0; t < TM; t++) {
    float a  = red[0][t] + red[1][t] + red[2][t] + red[3][t];
    float a2 = red[4][t] + red[5][t] + red[6][t] + red[7][t];
    float mu  = a * (1.f / CDIM);
    float var = a2 * (1.f / CDIM) - mu * mu;
    float rs  = rsqrtf(var + 1e-5f);
    n2[(size_t)(t0 + t) * CDIM + c] = f2bf((vals[t] - mu) * rs * lw[c] + lb[c]);
  }
}

// ---------------- GEMM1: hid = GELU(n2 @ W1 + b1), bf16 MFMA ----------------
// A = n2 [NTOK][256] bf16, BT = W1T [1024][256] bf16, C = hid [NTOK][1024] bf16.
// grid (8, 392): n-fastest so A m-tile stays in L2 across n-blocks.
__global__ __launch_bounds__(256) void gemm1_gelu_kernel(
    const short* __restrict__ A, const short* __restrict__ BT,
    const float* __restrict__ b1, short* __restrict__ hid)
{
  constexpr int K = 256;
  __shared__ short a_lds[128 * 72];
  __shared__ short b_lds[128 * 72];
  int n0 = blockIdx.x * 128, m0 = blockIdx.y * 128;
  int tid = threadIdx.x;
  int lane = tid & 63, wv = tid >> 6;
  int g = lane >> 4, l15 = lane & 15;
  int wm = wv >> 1, wn = wv & 1;

  f32x4 acc[4][4];
  #pragma unroll
  for (int i = 0; i < 4; i++)
    #pragma unroll
    for (int j = 0; j < 4; j++) acc[i][j] = (f32x4){0.f, 0.f, 0.f, 0.f};

  for (int kb = 0; kb < K; kb += 64) {
    __syncthreads();
    #pragma unroll
    for (int it = 0; it < 4; it++) {
      int i = tid + it * 256;
      int row = i >> 3, c8 = i & 7;
      *(bf16x8*)&a_lds[row * 72 + c8 * 8] =
          *(const bf16x8*)&A[(size_t)(m0 + row) * K + kb + c8 * 8];
      *(bf16x8*)&b_lds[row * 72 + c8 * 8] =
          *(const bf16x8*)&BT[(size_t)(n0 + row) * K + kb + c8 * 8];
    }
    __syncthreads();
    #pragma unroll
    for (int ks = 0; ks < 2; ks++) {
      bf16x8 af[4], bfr[4];
      #pragma unroll
      for (int i = 0; i < 4; i++)
        af[i] = *(bf16x8*)&a_lds[(wm * 64 + i * 16 + l15) * 72 + ks * 32 + g * 8];
      #pragma unroll
      for (int j = 0; j < 4; j++)
        bfr[j] = *(bf16x8*)&b_lds[(wn * 64 + j * 16 + l15) * 72 + ks * 32 + g * 8];
      #pragma unroll
      for (int i = 0; i < 4; i++)
        #pragma unroll
        for (int j = 0; j < 4; j++)
          acc[i][j] = __builtin_amdgcn_mfma_f32_16x16x32_bf16(af[i], bfr[j], acc[i][j], 0, 0, 0);
    }
  }

  #pragma unroll
  for (int j = 0; j < 4; j++) {
    int n = n0 + wn * 64 + j * 16 + l15;
    float bias = b1[n];
    #pragma unroll
    for (int i = 0; i < 4; i++) {
      #pragma unroll
      for (int r = 0; r < 4; r++) {
        int m = m0 + wm * 64 + i * 16 + g * 4 + r;
        float h = acc[i][j][r] + bias;
        h = 0.5f * h * (1.f + erff(h * 0.70710678118654752f));
        hid[(size_t)m * HID + n] = f2bf(h);
      }
    }
  }
}

// ---------------- GEMM2: out = x2 + hid @ W2 + b2, bf16 MFMA ----------------
// A = hid [NTOK][1024] bf16, BT = W2T [256][1024] bf16, out fp32 in-place (d_out).
__global__ __launch_bounds__(256) void gemm2_res_kernel(
    const short* __restrict__ A, const short* __restrict__ BT,
    const float* __restrict__ b2, float* __restrict__ out)
{
  constexpr int K = 1024;
  __shared__ short a_lds[128 * 72];
  __shared__ short b_lds[128 * 72];
  int n0 = blockIdx.x * 128, m0 = blockIdx.y * 128;
  int tid = threadIdx.x;
  int lane = tid & 63, wv = tid >> 6;
  int g = lane >> 4, l15 = lane & 15;
  int wm = wv >> 1, wn = wv & 1;

  f32x4 acc[4][4];
  #pragma unroll
  for (int i = 0; i < 4; i++)
    #pragma unroll
    for (int j = 0; j < 4; j++) acc[i][j] = (f32x4){0.f, 0.f, 0.f, 0.f};

  for (int kb = 0; kb < K; kb += 64) {
    __syncthreads();
    #pragma unroll
    for (int it = 0; it < 4; it++) {
      int i = tid + it * 256;
      int row = i >> 3, c8 = i & 7;
      *(bf16x8*)&a_lds[row * 72 + c8 * 8] =
          *(const bf16x8*)&A[(size_t)(m0 + row) * K + kb + c8 * 8];
      *(bf16x8*)&b_lds[row * 72 + c8 * 8] =
          *(const bf16x8*)&BT[(size_t)(n0 + row) * K + kb + c8 * 8];
    }
    __syncthreads();
    #pragma unroll
    for (int ks = 0; ks < 2; ks++) {
      bf16x8 af[4], bfr[4];
      #pragma unroll
      for (int i = 0; i < 4; i++)
        af[i] = *(bf16x8*)&a_lds[(wm * 64 + i * 16 + l15) * 72 + ks * 32 + g * 8];
      #pragma unroll
      for (int j = 0; j < 4; j++)
        bfr[j] = *(bf16x8*)&b_lds[(wn * 64 + j * 16 + l15) * 72 + ks * 32 + g * 8];
      #pragma unroll
      for (int i = 0; i < 4; i++)
        #pragma unroll
        for (int j = 0; j < 4; j++)
          acc[i][j] = __builtin_amdgcn_mfma_f32_16x16x32_bf16(af[i], bfr[j], acc[i][j], 0, 0, 0);
    }
  }

  #pragma unroll
  for (int j = 0; j < 4; j++) {
    int n = n0 + wn * 64 + j * 16 + l15;
    float bias = b2[n];
    #pragma unroll
    for (int i = 0; i < 4; i++) {
      #pragma unroll
      for (int r = 0; r < 4; r++) {
        int m = m0 + wm * 64 + i * 16 + g * 4 + r;
        size_t idx = (size_t)m * CDIM + n;
        out[idx] = out[idx] + acc[i][j][r] + bias;
      }
    }
  }
}

}  // namespace

extern "C" void kernel_launch(void* const* d_in, const int* in_sizes, int n_in,
                              void* d_out, int out_size, void* d_ws, size_t ws_size,
                              hipStream_t stream)
{
  const float* x    = (const float*)d_in[0];
  const float* ln1w = (const float*)d_in[3];
  const float* ln1b = (const float*)d_in[4];
  const float* ln2w = (const float*)d_in[5];
  const float* ln2b = (const float*)d_in[6];
  const float* btbl = (const float*)d_in[7];
  const float* lwq  = (const float*)d_in[8];
  const float* lbq  = (const float*)d_in[9];
  const float* lwk  = (const float*)d_in[10];
  const float* lbk  = (const float*)d_in[11];
  const float* lwv  = (const float*)d_in[12];
  const float* lbv  = (const float*)d_in[13];
  const float* lwp  = (const float*)d_in[14];
  const float* lbp  = (const float*)d_in[15];
  const float* vwq  = (const float*)d_in[16];
  const float* vbq  = (const float*)d_in[17];
  const float* vwk  = (const float*)d_in[18];
  const float* vbk  = (const float*)d_in[19];
  const float* vwv  = (const float*)d_in[20];
  const float* vbv  = (const float*)d_in[21];
  const float* vwp  = (const float*)d_in[22];
  const float* vbp  = (const float*)d_in[23];
  const float* hwq  = (const float*)d_in[24];
  const float* hbq  = (const float*)d_in[25];
  const float* hwk  = (const float*)d_in[26];
  const float* hbk  = (const float*)d_in[27];
  const float* hwv  = (const float*)d_in[28];
  const float* hbv  = (const float*)d_in[29];
  const float* hwp  = (const float*)d_in[30];
  const float* hbp  = (const float*)d_in[31];
  const float* fc1w = (const float*)d_in[32];
  const float* fc1b = (const float*)d_in[33];
  const float* fc2w = (const float*)d_in[34];
  const float* fc2b = (const float*)d_in[35];

  float* ws = (float*)d_ws;
  size_t off = 0;
  auto alloc = [&](size_t n) { float* p = ws + off; off += n; return p; };
  float* h1  = alloc((size_t)NTOK * CDIM);
  float* ql  = alloc((size_t)NTOK * LCH);
  float* klb = alloc((size_t)NTOK * LCH);
  float* vlb = alloc((size_t)NTOK * LCH);
  float* olb = alloc((size_t)NTOK * LCH);
  float* qv  = alloc((size_t)NTOK * ACH);
  float* kvb = alloc((size_t)NTOK * ACH);
  float* vvb = alloc((size_t)NTOK * ACH);
  float* ovb = alloc((size_t)NTOK * ACH);
  float* qh  = alloc((size_t)NTOK * ACH);
  float* khb = alloc((size_t)NTOK * ACH);
  float* vhb = alloc((size_t)NTOK * ACH);
  float* ohb = alloc((size_t)NTOK * ACH);
  // bf16 weight buffers at tail (+1 MB)
  short* w1t = (short*)(ws + off);                 // [1024][256]
  short* w2t = w1t + (size_t)CDIM * HID;           // [256][1024]
  // bf16 n2 / hid alias the h1/ql/klb/vlb regions (dead after loc_attn):
  short* n2  = (short*)ws;                         // [NTOK][256]  bytes [0, 25.7M)
  short* hid = n2 + (size_t)NTOK * CDIM;           // [NTOK][1024] bytes [25.7M, 128.45M) = end of vlb
  float* x2  = (float*)d_out;

  conv_w_kernel<<<(CDIM * HID + 255) / 256, 256, 0, stream>>>(fc1w, w1t, CDIM, HID);
  conv_w_kernel<<<(CDIM * HID + 255) / 256, 256, 0, stream>>>(fc2w, w2t, HID, CDIM);
  ln1_kernel<<<NTOK, 256, 0, stream>>>(x, ln1w, ln1b, h1);
  qkv_kernel<128><<<NTOK / 4, 256, 0, stream>>>(h1, 0,   lwq, lbq, lwk, lbk, lwv, lbv,
                                                ql, klb, vlb, QSC);
  qkv_kernel<64><<<NTOK / 4, 256, 0, stream>>>(h1, 128, vwq, vbq, vwk, vbk, vwv, vbv,
                                               qv, kvb, vvb, QSC);
  qkv_kernel<64><<<NTOK / 4, 256, 0, stream>>>(h1, 192, hwq, hbq, hwk, hbk, hwv, hbv,
                                               qh, khb, vhb, QSC);
  loc_attn_mfma<<<4096, 256, 0, stream>>>(ql, klb, vlb, lbk, lbv, btbl, olb);
  axial_attn_kernel<<<896, 256, 0, stream>>>(qv, kvb, vvb, ovb, 1);
  axial_attn_kernel<<<896, 256, 0, stream>>>(qh, khb, vhb, ohb, 0);
  proj_res_ln2_kernel<<<NTOK / 4, 256, 0, stream>>>(x, olb, ovb, ohb,
                                                    lwp, lbp, vwp, vbp, hwp, hbp,
                                                    ln2w, ln2b, x2, n2);
  gemm1_gelu_kernel<<<dim3(HID / 128, NTOK / 128), 256, 0, stream>>>(n2, w1t, fc1b, hid);
  gemm2_res_kernel<<<dim3(CDIM / 128, NTOK / 128), 256, 0, stream>>>(hid, w2t, fc2b, x2);
}

// Round 4
// 1343.822 us; speedup vs baseline: 4.0989x; 1.3716x over previous
//
#include <hip/hip_runtime.h>
#include <math.h>

// MixAxialPOLABlock — round 4:
//  * loc_attn: remove dynamic register-array indexing (acc[] was spilling to
//    scratch -> 2.4 GB HBM writes). PV loop fully unrolled, acc stays in VGPRs.
//  * qkv projections -> bf16 MFMA GEMMs (combined q|k|v weight, fused bias+scale).
//  * ln1 emits bf16 directly (only consumer is the qkv GEMMs).

namespace {

constexpr int IMG  = 112;
constexpr int NTOK = 4 * IMG * IMG;   // 50176
constexpr int CDIM = 256;
constexpr int LCH  = 128;
constexpr int ACH  = 64;
constexpr int HID  = 1024;
constexpr float QSC = 0.17677669529663687f;  // 1/sqrt(32)

typedef __attribute__((ext_vector_type(8))) short bf16x8;
typedef __attribute__((ext_vector_type(4))) float f32x4;

__device__ inline short f2bf(float f) {
  union { float f; unsigned u; } c; c.f = f;
  unsigned u = c.u;
  return (short)((u + 0x7fffu + ((u >> 16) & 1u)) >> 16);
}

// ------------- weight transpose + bf16 convert: src[K][N] -> dst[N][K] -------------
__global__ __launch_bounds__(256) void conv_w_kernel(
    const float* __restrict__ src, short* __restrict__ dst, int K, int N)
{
  int idx = blockIdx.x * 256 + threadIdx.x;
  if (idx < K * N) {
    int n = idx / K, k = idx - n * K;
    dst[idx] = f2bf(src[(size_t)k * N + n]);
  }
}

// ---------------- LayerNorm (ln1) -> bf16 : one block per token ----------------
__global__ __launch_bounds__(256) void ln1_kernel(
    const float* __restrict__ x, const float* __restrict__ w,
    const float* __restrict__ b, short* __restrict__ out)
{
  int tok = blockIdx.x;
  int c = threadIdx.x;
  size_t idx = (size_t)tok * CDIM + c;
  float v = x[idx];
  float s = v, s2 = v * v;
  #pragma unroll
  for (int o = 32; o; o >>= 1) { s += __shfl_xor(s, o); s2 += __shfl_xor(s2, o); }
  __shared__ float red[8];
  int lane = c & 63, wv = c >> 6;
  if (lane == 0) { red[wv] = s; red[4 + wv] = s2; }
  __syncthreads();
  float a  = red[0] + red[1] + red[2] + red[3];
  float a2 = red[4] + red[5] + red[6] + red[7];
  float mu  = a * (1.f / CDIM);
  float var = a2 * (1.f / CDIM) - mu * mu;
  float rs  = rsqrtf(var + 1e-5f);
  out[idx] = f2bf((v - mu) * rs * w[c] + b[c]);
}

// ------------- q/k/v projection as bf16 MFMA GEMM -------------
// A = h1b[:, coff:coff+KD] (row stride CDIM), BT = combined [3*GD(+pad)][KD]
// (rows: wq^T | wk^T | wv^T). Tile 128x128, BK=64. Epilogue routes column
// ranges to q/k/v fp32 buffers (wave-uniform), bias + qscale fused.
template<int KD, int GD>
__global__ __launch_bounds__(256) void qkv_gemm_kernel(
    const short* __restrict__ h1b, int coff, const short* __restrict__ BT,
    const float* __restrict__ bq, const float* __restrict__ bk,
    const float* __restrict__ bv,
    float* __restrict__ qo, float* __restrict__ ko, float* __restrict__ vo,
    float qscale)
{
  __shared__ short a_lds[128 * 72];
  __shared__ short b_lds[128 * 72];
  int n0 = blockIdx.x * 128, m0 = blockIdx.y * 128;
  int tid = threadIdx.x;
  int lane = tid & 63, wv = tid >> 6;
  int g = lane >> 4, l15 = lane & 15;
  int wm = wv >> 1, wn = wv & 1;

  f32x4 acc[4][4];
  #pragma unroll
  for (int i = 0; i < 4; i++)
    #pragma unroll
    for (int j = 0; j < 4; j++) acc[i][j] = (f32x4){0.f, 0.f, 0.f, 0.f};

  for (int kb = 0; kb < KD; kb += 64) {
    __syncthreads();
    #pragma unroll
    for (int it = 0; it < 4; it++) {
      int i = tid + it * 256;
      int row = i >> 3, c8 = i & 7;
      *(bf16x8*)&a_lds[row * 72 + c8 * 8] =
          *(const bf16x8*)&h1b[(size_t)(m0 + row) * CDIM + coff + kb + c8 * 8];
      *(bf16x8*)&b_lds[row * 72 + c8 * 8] =
          *(const bf16x8*)&BT[(size_t)(n0 + row) * KD + kb + c8 * 8];
    }
    __syncthreads();
    #pragma unroll
    for (int ks = 0; ks < 2; ks++) {
      bf16x8 af[4], bfr[4];
      #pragma unroll
      for (int i = 0; i < 4; i++)
        af[i] = *(bf16x8*)&a_lds[(wm * 64 + i * 16 + l15) * 72 + ks * 32 + g * 8];
      #pragma unroll
      for (int j = 0; j < 4; j++)
        bfr[j] = *(bf16x8*)&b_lds[(wn * 64 + j * 16 + l15) * 72 + ks * 32 + g * 8];
      #pragma unroll
      for (int i = 0; i < 4; i++)
        #pragma unroll
        for (int j = 0; j < 4; j++)
          acc[i][j] = __builtin_amdgcn_mfma_f32_16x16x32_bf16(af[i], bfr[j], acc[i][j], 0, 0, 0);
    }
  }

  #pragma unroll
  for (int j = 0; j < 4; j++) {
    int ng = n0 + wn * 64 + j * 16 + l15;
    int sel = ng / GD;          // wave-uniform (GD is 64 or 128)
    int col = ng % GD;
    if (sel < 3) {
      float* op = sel == 0 ? qo : (sel == 1 ? ko : vo);
      const float* bp = sel == 0 ? bq : (sel == 1 ? bk : bv);
      float sc = sel == 0 ? qscale : 1.f;
      float bias = bp[col];
      #pragma unroll
      for (int i = 0; i < 4; i++) {
        #pragma unroll
        for (int r = 0; r < 4; r++) {
          int m = m0 + wm * 64 + i * 16 + g * 4 + r;
          op[(size_t)m * GD + col] = (acc[i][j][r] + bias) * sc;
        }
      }
    }
  }
}

// ---------------- local window attention, MFMA bf16 ----------------
__global__ __launch_bounds__(256) void loc_attn_mfma(
    const float* __restrict__ ql, const float* __restrict__ kl,
    const float* __restrict__ vl, const float* __restrict__ bk,
    const float* __restrict__ bv, const float* __restrict__ btbl,
    float* __restrict__ ol)
{
  constexpr int KSTR = 40;
  constexpr int VSTR = 456;
  constexpr int PSTR = 40;
  __shared__ short kv_lds[448 * KSTR];
  __shared__ float bias_lds[736];
  __shared__ short p_lds[4][16 * PSTR];

  int head = blockIdx.x & 3;
  int wi = blockIdx.x >> 2;
  int wx = wi & 15, wy = (wi >> 4) & 15, b = wi >> 8;
  int tid = threadIdx.x;
  int lane = tid & 63, wv = tid >> 6;
  int g = lane >> 4, l15 = lane & 15;
  const float* bkh = bk + head * 32;
  const float* bvh = bv + head * 32;

  for (int it = tid; it < 448 * 4; it += 256) {
    int key = it >> 2, dg = it & 3;
    float buf[8];
    if (key < 441) {
      int ky = key / 21, kx = key - ky * 21;
      int rr = wy * 7 + ky - 7, cc = wx * 7 + kx - 7;
      const float* src;
      if ((unsigned)rr < (unsigned)IMG && (unsigned)cc < (unsigned)IMG)
        src = kl + ((size_t)((b * IMG + rr) * IMG + cc)) * LCH + head * 32 + dg * 8;
      else
        src = bkh + dg * 8;
      float4 a0 = *(const float4*)src;
      float4 a1 = *(const float4*)(src + 4);
      buf[0] = a0.x; buf[1] = a0.y; buf[2] = a0.z; buf[3] = a0.w;
      buf[4] = a1.x; buf[5] = a1.y; buf[6] = a1.z; buf[7] = a1.w;
    } else {
      #pragma unroll
      for (int j = 0; j < 8; j++) buf[j] = 0.f;
    }
    bf16x8 f;
    #pragma unroll
    for (int j = 0; j < 8; j++) f[j] = f2bf(buf[j]);
    *(bf16x8*)(&kv_lds[key * KSTR + dg * 8]) = f;
  }
  for (int i = tid; i < 729; i += 256) bias_lds[i] = btbl[i * 4 + head];

  int q0 = wv * 16 + l15;
  int qc = q0 < 49 ? q0 : 48;
  int qy0 = qc / 7, qx0 = qc - qy0 * 7;
  size_t qbase = ((size_t)((b * IMG + wy * 7 + qy0) * IMG + wx * 7 + qx0)) * LCH
                 + head * 32 + g * 8;
  float4 qa = *(const float4*)(ql + qbase);
  float4 qb = *(const float4*)(ql + qbase + 4);
  bf16x8 qfrag;
  qfrag[0] = f2bf(qa.x); qfrag[1] = f2bf(qa.y); qfrag[2] = f2bf(qa.z); qfrag[3] = f2bf(qa.w);
  qfrag[4] = f2bf(qb.x); qfrag[5] = f2bf(qb.y); qfrag[6] = f2bf(qb.z); qfrag[7] = f2bf(qb.w);

  __syncthreads();

  // S = Q.K^T : all indices compile-time constant -> acc stays in VGPRs.
  f32x4 acc[28];
  #pragma unroll
  for (int n = 0; n < 28; n++) {
    bf16x8 kfrag = *(bf16x8*)(&kv_lds[(n * 16 + l15) * KSTR + g * 8]);
    f32x4 z = {0.f, 0.f, 0.f, 0.f};
    acc[n] = __builtin_amdgcn_mfma_f32_16x16x32_bf16(qfrag, kfrag, z, 0, 0, 0);
  }

  float rinv[4];
  #pragma unroll
  for (int r = 0; r < 4; r++) {
    int q = wv * 16 + g * 4 + r;
    int qq = q < 49 ? q : 0;
    int qy = qq / 7, qx = qq - qy * 7;
    float m = -1e30f;
    #pragma unroll
    for (int n = 0; n < 28; n++) {
      int key = n * 16 + l15;
      if (key < 441) {
        int ky = key / 21, kx = key - ky * 21;
        float s = acc[n][r] + bias_lds[(qy - ky + 20) * 27 + (qx - kx + 20)];
        acc[n][r] = s;
        m = fmaxf(m, s);
      } else {
        acc[n][r] = -1e30f;
      }
    }
    m = fmaxf(m, __shfl_xor(m, 1));
    m = fmaxf(m, __shfl_xor(m, 2));
    m = fmaxf(m, __shfl_xor(m, 4));
    m = fmaxf(m, __shfl_xor(m, 8));
    float sum = 0.f;
    #pragma unroll
    for (int n = 0; n < 28; n++) {
      float p = (acc[n][r] > -1e29f) ? __expf(acc[n][r] - m) : 0.f;
      acc[n][r] = p;
      sum += p;
    }
    sum += __shfl_xor(sum, 1);
    sum += __shfl_xor(sum, 2);
    sum += __shfl_xor(sum, 4);
    sum += __shfl_xor(sum, 8);
    rinv[r] = 1.f / sum;
  }

  __syncthreads();

  for (int it = tid; it < 448 * 4; it += 256) {
    int key = it >> 2, dg = it & 3;
    float buf[8];
    if (key < 441) {
      int ky = key / 21, kx = key - ky * 21;
      int rr = wy * 7 + ky - 7, cc = wx * 7 + kx - 7;
      const float* src;
      if ((unsigned)rr < (unsigned)IMG && (unsigned)cc < (unsigned)IMG)
        src = vl + ((size_t)((b * IMG + rr) * IMG + cc)) * LCH + head * 32 + dg * 8;
      else
        src = bvh + dg * 8;
      float4 a0 = *(const float4*)src;
      float4 a1 = *(const float4*)(src + 4);
      buf[0] = a0.x; buf[1] = a0.y; buf[2] = a0.z; buf[3] = a0.w;
      buf[4] = a1.x; buf[5] = a1.y; buf[6] = a1.z; buf[7] = a1.w;
    } else {
      #pragma unroll
      for (int j = 0; j < 8; j++) buf[j] = 0.f;
    }
    #pragma unroll
    for (int j = 0; j < 8; j++) kv_lds[(dg * 8 + j) * VSTR + key] = f2bf(buf[j]);
  }
  __syncthreads();

  // O = P.V : fully unrolled -> constant acc indices (no scratch).
  f32x4 oacc[2];
  oacc[0] = (f32x4){0.f, 0.f, 0.f, 0.f};
  oacc[1] = (f32x4){0.f, 0.f, 0.f, 0.f};
  short* pw = p_lds[wv];
  #pragma unroll
  for (int c = 0; c < 14; c++) {
    #pragma unroll
    for (int t = 0; t < 2; t++) {
      f32x4 pv = acc[2 * c + t];
      #pragma unroll
      for (int r = 0; r < 4; r++)
        pw[(g * 4 + r) * PSTR + t * 16 + l15] = f2bf(pv[r]);
    }
    asm volatile("s_waitcnt lgkmcnt(0)" ::: "memory");
    bf16x8 pfrag = *(bf16x8*)(&pw[l15 * PSTR + g * 8]);
    #pragma unroll
    for (int nt = 0; nt < 2; nt++) {
      bf16x8 vfrag = *(bf16x8*)(&kv_lds[(nt * 16 + l15) * VSTR + c * 32 + g * 8]);
      oacc[nt] = __builtin_amdgcn_mfma_f32_16x16x32_bf16(pfrag, vfrag, oacc[nt], 0, 0, 0);
    }
  }

  #pragma unroll
  for (int r = 0; r < 4; r++) {
    int q = wv * 16 + g * 4 + r;
    if (q < 49) {
      int qy = q / 7, qx = q - qy * 7;
      size_t obase = ((size_t)((b * IMG + wy * 7 + qy) * IMG + wx * 7 + qx)) * LCH
                     + head * 32;
      ol[obase + l15]      = oacc[0][r] * rinv[r];
      ol[obase + 16 + l15] = oacc[1][r] * rinv[r];
    }
  }
}

// ---------------- axial attention (vert: over h; horz: over w) ----------------
__global__ __launch_bounds__(256) void axial_attn_kernel(
    const float* __restrict__ q, const float* __restrict__ k,
    const float* __restrict__ v, float* __restrict__ out, int vert)
{
  int head = blockIdx.x & 1;
  int s = blockIdx.x >> 1;
  int b = s / IMG, t = s % IMG;
  size_t base; int stride;
  if (vert) { base = ((size_t)b * IMG * IMG + t) * ACH; stride = IMG * ACH; }
  else      { base = ((size_t)(b * IMG + t)) * (size_t)IMG * ACH; stride = ACH; }
  base += head * 32;
  int lane = threadIdx.x & 63, wvid = threadIdx.x >> 6;
  __shared__ float qs[4][32];
  __shared__ float probs[4][112];

  for (int qi = wvid; qi < IMG; qi += 4) {
    __syncthreads();
    if (lane < 32) qs[wvid][lane] = q[base + (size_t)qi * stride + lane];
    __syncthreads();
    float qreg[32];
    #pragma unroll
    for (int d = 0; d < 32; d++) qreg[d] = qs[wvid][d];
    float lg[2];
    float m = -1e30f;
    #pragma unroll
    for (int jj = 0; jj < 2; jj++) {
      int j = jj * 64 + lane;
      if (j < IMG) {
        const float* kp = k + base + (size_t)j * stride;
        float acc = 0.f;
        #pragma unroll
        for (int d = 0; d < 32; d++) acc += qreg[d] * kp[d];
        lg[jj] = acc;
        m = fmaxf(m, acc);
      }
    }
    #pragma unroll
    for (int o = 32; o; o >>= 1) m = fmaxf(m, __shfl_xor(m, o));
    float ssum = 0.f;
    #pragma unroll
    for (int jj = 0; jj < 2; jj++) {
      int j = jj * 64 + lane;
      if (j < IMG) {
        float p = __expf(lg[jj] - m);
        probs[wvid][j] = p;
        ssum += p;
      }
    }
    #pragma unroll
    for (int o = 32; o; o >>= 1) ssum += __shfl_xor(ssum, o);
    float inv = 1.f / ssum;
    __syncthreads();
    int d = lane & 31, half = lane >> 5;
    float acc = 0.f;
    for (int j = half; j < IMG; j += 2)
      acc += probs[wvid][j] * v[base + (size_t)j * stride + d];
    acc += __shfl_xor(acc, 32);
    if (half == 0) out[base + (size_t)qi * stride + d] = acc * inv;
  }
}

// ------ output projections + residual concat -> x2 (d_out) + fused LN2 -> n2 bf16 ------
__global__ __launch_bounds__(256) void proj_res_ln2_kernel(
    const float* __restrict__ x, const float* __restrict__ ol,
    const float* __restrict__ ov, const float* __restrict__ oh,
    const float* __restrict__ wpl, const float* __restrict__ bpl,
    const float* __restrict__ wpv, const float* __restrict__ bpv,
    const float* __restrict__ wph, const float* __restrict__ bph,
    const float* __restrict__ lw, const float* __restrict__ lb,
    float* __restrict__ x2, short* __restrict__ n2)
{
  constexpr int TM = 4;
  __shared__ float rl[TM][LCH];
  __shared__ float rv[TM][ACH];
  __shared__ float rh[TM][ACH];
  __shared__ float red[8][TM];
  int t0 = blockIdx.x * TM;
  for (int i = threadIdx.x; i < TM * LCH; i += 256) {
    int t = i >> 7, c = i & 127;
    rl[t][c] = ol[(size_t)(t0 + t) * LCH + c];
  }
  for (int i = threadIdx.x; i < TM * ACH; i += 256) {
    int t = i >> 6, c = i & 63;
    rv[t][c] = ov[(size_t)(t0 + t) * ACH + c];
    rh[t][c] = oh[(size_t)(t0 + t) * ACH + c];
  }
  __syncthreads();
  int c = threadIdx.x;
  float acc[TM];
  if (c < 128) {
    #pragma unroll
    for (int t = 0; t < TM; t++) acc[t] = bpl[c];
    for (int kk = 0; kk < LCH; kk++) {
      float wval = wpl[(size_t)kk * LCH + c];
      #pragma unroll
      for (int t = 0; t < TM; t++) acc[t] += rl[t][kk] * wval;
    }
  } else if (c < 192) {
    int cc = c - 128;
    #pragma unroll
    for (int t = 0; t < TM; t++) acc[t] = bpv[cc];
    for (int kk = 0; kk < ACH; kk++) {
      float wval = wpv[(size_t)kk * ACH + cc];
      #pragma unroll
      for (int t = 0; t < TM; t++) acc[t] += rv[t][kk] * wval;
    }
  } else {
    int cc = c - 192;
    #pragma unroll
    for (int t = 0; t < TM; t++) acc[t] = bph[cc];
    for (int kk = 0; kk < ACH; kk++) {
      float wval = wph[(size_t)kk * ACH + cc];
      #pragma unroll
      for (int t = 0; t < TM; t++) acc[t] += rh[t][kk] * wval;
    }
  }
  float vals[TM];
  #pragma unroll
  for (int t = 0; t < TM; t++) {
    size_t idx = (size_t)(t0 + t) * CDIM + c;
    vals[t] = x[idx] + acc[t];
    x2[idx] = vals[t];
  }
  int lane = c & 63, wvid = c >> 6;
  float s[TM], s2[TM];
  #pragma unroll
  for (int t = 0; t < TM; t++) { s[t] = vals[t]; s2[t] = vals[t] * vals[t]; }
  #pragma unroll
  for (int o = 32; o; o >>= 1) {
    #pragma unroll
    for (int t = 0; t < TM; t++) { s[t] += __shfl_xor(s[t], o); s2[t] += __shfl_xor(s2[t], o); }
  }
  if (lane == 0) {
    #pragma unroll
    for (int t = 0; t < TM; t++) { red[wvid][t] = s[t]; red[4 + wvid][t] = s2[t]; }
  }
  __syncthreads();
  #pragma unroll
  for (int t = 0; t < TM; t++) {
    float a  = red[0][t] + red[1][t] + red[2][t] + red[3][t];
    float a2 = red[4][t] + red[5][t] + red[6][t] + red[7][t];
    float mu  = a * (1.f / CDIM);
    float var = a2 * (1.f / CDIM) - mu * mu;
    float rs  = rsqrtf(var + 1e-5f);
    n2[(size_t)(t0 + t) * CDIM + c] = f2bf((vals[t] - mu) * rs * lw[c] + lb[c]);
  }
}

// ---------------- GEMM1: hid = GELU(n2 @ W1 + b1), bf16 MFMA ----------------
__global__ __launch_bounds__(256) void gemm1_gelu_kernel(
    const short* __restrict__ A, const short* __restrict__ BT,
    const float* __restrict__ b1, short* __restrict__ hid)
{
  constexpr int K = 256;
  __shared__ short a_lds[128 * 72];
  __shared__ short b_lds[128 * 72];
  int n0 = blockIdx.x * 128, m0 = blockIdx.y * 128;
  int tid = threadIdx.x;
  int lane = tid & 63, wv = tid >> 6;
  int g = lane >> 4, l15 = lane & 15;
  int wm = wv >> 1, wn = wv & 1;

  f32x4 acc[4][4];
  #pragma unroll
  for (int i = 0; i < 4; i++)
    #pragma unroll
    for (int j = 0; j < 4; j++) acc[i][j] = (f32x4){0.f, 0.f, 0.f, 0.f};

  for (int kb = 0; kb < K; kb += 64) {
    __syncthreads();
    #pragma unroll
    for (int it = 0; it < 4; it++) {
      int i = tid + it * 256;
      int row = i >> 3, c8 = i & 7;
      *(bf16x8*)&a_lds[row * 72 + c8 * 8] =
          *(const bf16x8*)&A[(size_t)(m0 + row) * K + kb + c8 * 8];
      *(bf16x8*)&b_lds[row * 72 + c8 * 8] =
          *(const bf16x8*)&BT[(size_t)(n0 + row) * K + kb + c8 * 8];
    }
    __syncthreads();
    #pragma unroll
    for (int ks = 0; ks < 2; ks++) {
      bf16x8 af[4], bfr[4];
      #pragma unroll
      for (int i = 0; i < 4; i++)
        af[i] = *(bf16x8*)&a_lds[(wm * 64 + i * 16 + l15) * 72 + ks * 32 + g * 8];
      #pragma unroll
      for (int j = 0; j < 4; j++)
        bfr[j] = *(bf16x8*)&b_lds[(wn * 64 + j * 16 + l15) * 72 + ks * 32 + g * 8];
      #pragma unroll
      for (int i = 0; i < 4; i++)
        #pragma unroll
        for (int j = 0; j < 4; j++)
          acc[i][j] = __builtin_amdgcn_mfma_f32_16x16x32_bf16(af[i], bfr[j], acc[i][j], 0, 0, 0);
    }
  }

  #pragma unroll
  for (int j = 0; j < 4; j++) {
    int n = n0 + wn * 64 + j * 16 + l15;
    float bias = b1[n];
    #pragma unroll
    for (int i = 0; i < 4; i++) {
      #pragma unroll
      for (int r = 0; r < 4; r++) {
        int m = m0 + wm * 64 + i * 16 + g * 4 + r;
        float h = acc[i][j][r] + bias;
        h = 0.5f * h * (1.f + erff(h * 0.70710678118654752f));
        hid[(size_t)m * HID + n] = f2bf(h);
      }
    }
  }
}

// ---------------- GEMM2: out = x2 + hid @ W2 + b2, bf16 MFMA ----------------
__global__ __launch_bounds__(256) void gemm2_res_kernel(
    const short* __restrict__ A, const short* __restrict__ BT,
    const float* __restrict__ b2, float* __restrict__ out)
{
  constexpr int K = 1024;
  __shared__ short a_lds[128 * 72];
  __shared__ short b_lds[128 * 72];
  int n0 = blockIdx.x * 128, m0 = blockIdx.y * 128;
  int tid = threadIdx.x;
  int lane = tid & 63, wv = tid >> 6;
  int g = lane >> 4, l15 = lane & 15;
  int wm = wv >> 1, wn = wv & 1;

  f32x4 acc[4][4];
  #pragma unroll
  for (int i = 0; i < 4; i++)
    #pragma unroll
    for (int j = 0; j < 4; j++) acc[i][j] = (f32x4){0.f, 0.f, 0.f, 0.f};

  for (int kb = 0; kb < K; kb += 64) {
    __syncthreads();
    #pragma unroll
    for (int it = 0; it < 4; it++) {
      int i = tid + it * 256;
      int row = i >> 3, c8 = i & 7;
      *(bf16x8*)&a_lds[row * 72 + c8 * 8] =
          *(const bf16x8*)&A[(size_t)(m0 + row) * K + kb + c8 * 8];
      *(bf16x8*)&b_lds[row * 72 + c8 * 8] =
          *(const bf16x8*)&BT[(size_t)(n0 + row) * K + kb + c8 * 8];
    }
    __syncthreads();
    #pragma unroll
    for (int ks = 0; ks < 2; ks++) {
      bf16x8 af[4], bfr[4];
      #pragma unroll
      for (int i = 0; i < 4; i++)
        af[i] = *(bf16x8*)&a_lds[(wm * 64 + i * 16 + l15) * 72 + ks * 32 + g * 8];
      #pragma unroll
      for (int j = 0; j < 4; j++)
        bfr[j] = *(bf16x8*)&b_lds[(wn * 64 + j * 16 + l15) * 72 + ks * 32 + g * 8];
      #pragma unroll
      for (int i = 0; i < 4; i++)
        #pragma unroll
        for (int j = 0; j < 4; j++)
          acc[i][j] = __builtin_amdgcn_mfma_f32_16x16x32_bf16(af[i], bfr[j], acc[i][j], 0, 0, 0);
    }
  }

  #pragma unroll
  for (int j = 0; j < 4; j++) {
    int n = n0 + wn * 64 + j * 16 + l15;
    float bias = b2[n];
    #pragma unroll
    for (int i = 0; i < 4; i++) {
      #pragma unroll
      for (int r = 0; r < 4; r++) {
        int m = m0 + wm * 64 + i * 16 + g * 4 + r;
        size_t idx = (size_t)m * CDIM + n;
        out[idx] = out[idx] + acc[i][j][r] + bias;
      }
    }
  }
}

}  // namespace

extern "C" void kernel_launch(void* const* d_in, const int* in_sizes, int n_in,
                              void* d_out, int out_size, void* d_ws, size_t ws_size,
                              hipStream_t stream)
{
  const float* x    = (const float*)d_in[0];
  const float* ln1w = (const float*)d_in[3];
  const float* ln1b = (const float*)d_in[4];
  const float* ln2w = (const float*)d_in[5];
  const float* ln2b = (const float*)d_in[6];
  const float* btbl = (const float*)d_in[7];
  const float* lwq  = (const float*)d_in[8];
  const float* lbq  = (const float*)d_in[9];
  const float* lwk  = (const float*)d_in[10];
  const float* lbk  = (const float*)d_in[11];
  const float* lwv  = (const float*)d_in[12];
  const float* lbv  = (const float*)d_in[13];
  const float* lwp  = (const float*)d_in[14];
  const float* lbp  = (const float*)d_in[15];
  const float* vwq  = (const float*)d_in[16];
  const float* vbq  = (const float*)d_in[17];
  const float* vwk  = (const float*)d_in[18];
  const float* vbk  = (const float*)d_in[19];
  const float* vwv  = (const float*)d_in[20];
  const float* vbv  = (const float*)d_in[21];
  const float* vwp  = (const float*)d_in[22];
  const float* vbp  = (const float*)d_in[23];
  const float* hwq  = (const float*)d_in[24];
  const float* hbq  = (const float*)d_in[25];
  const float* hwk  = (const float*)d_in[26];
  const float* hbk  = (const float*)d_in[27];
  const float* hwv  = (const float*)d_in[28];
  const float* hbv  = (const float*)d_in[29];
  const float* hwp  = (const float*)d_in[30];
  const float* hbp  = (const float*)d_in[31];
  const float* fc1w = (const float*)d_in[32];
  const float* fc1b = (const float*)d_in[33];
  const float* fc2w = (const float*)d_in[34];
  const float* fc2b = (const float*)d_in[35];

  float* ws = (float*)d_ws;
  size_t off = 0;
  auto alloc = [&](size_t n) { float* p = ws + off; off += n; return p; };
  float* h1f = alloc((size_t)NTOK * CDIM);   // first half used as bf16 h1b
  float* ql  = alloc((size_t)NTOK * LCH);
  float* klb = alloc((size_t)NTOK * LCH);
  float* vlb = alloc((size_t)NTOK * LCH);
  float* olb = alloc((size_t)NTOK * LCH);
  float* qv  = alloc((size_t)NTOK * ACH);
  float* kvb = alloc((size_t)NTOK * ACH);
  float* vvb = alloc((size_t)NTOK * ACH);
  float* ovb = alloc((size_t)NTOK * ACH);
  float* qh  = alloc((size_t)NTOK * ACH);
  float* khb = alloc((size_t)NTOK * ACH);
  float* vhb = alloc((size_t)NTOK * ACH);
  float* ohb = alloc((size_t)NTOK * ACH);
  // bf16 weight buffers at tail
  short* w1t    = (short*)(ws + off);                  // [1024][256]
  short* w2t    = w1t + (size_t)CDIM * HID;            // [256][1024]
  short* loc_bt = w2t + (size_t)CDIM * HID;            // [384][128] = wq^T|wk^T|wv^T
  short* axv_bt = loc_bt + 384 * 128;                  // [256][64] (rows 192+ unused)
  short* axh_bt = axv_bt + 256 * 64;                   // [256][64]
  // bf16 activation aliases
  short* h1b = (short*)h1f;                            // [NTOK][256] bf16 (qkv input)
  short* n2  = (short*)ws;                             // [NTOK][256] (aliases h1b; written after last h1b read)
  short* hid = n2 + (size_t)NTOK * CDIM;               // [NTOK][1024] (aliases ql/klb/vlb)
  float* x2  = (float*)d_out;

  // weight prep
  conv_w_kernel<<<(CDIM * HID + 255) / 256, 256, 0, stream>>>(fc1w, w1t, CDIM, HID);
  conv_w_kernel<<<(CDIM * HID + 255) / 256, 256, 0, stream>>>(fc2w, w2t, HID, CDIM);
  conv_w_kernel<<<64, 256, 0, stream>>>(lwq, loc_bt,            128, 128);
  conv_w_kernel<<<64, 256, 0, stream>>>(lwk, loc_bt + 128*128,  128, 128);
  conv_w_kernel<<<64, 256, 0, stream>>>(lwv, loc_bt + 2*128*128,128, 128);
  conv_w_kernel<<<16, 256, 0, stream>>>(vwq, axv_bt,            64, 64);
  conv_w_kernel<<<16, 256, 0, stream>>>(vwk, axv_bt + 64*64,    64, 64);
  conv_w_kernel<<<16, 256, 0, stream>>>(vwv, axv_bt + 2*64*64,  64, 64);
  conv_w_kernel<<<16, 256, 0, stream>>>(hwq, axh_bt,            64, 64);
  conv_w_kernel<<<16, 256, 0, stream>>>(hwk, axh_bt + 64*64,    64, 64);
  conv_w_kernel<<<16, 256, 0, stream>>>(hwv, axh_bt + 2*64*64,  64, 64);

  ln1_kernel<<<NTOK, 256, 0, stream>>>(x, ln1w, ln1b, h1b);
  qkv_gemm_kernel<128,128><<<dim3(3, NTOK/128), 256, 0, stream>>>(
      h1b, 0, loc_bt, lbq, lbk, lbv, ql, klb, vlb, QSC);
  qkv_gemm_kernel<64,64><<<dim3(2, NTOK/128), 256, 0, stream>>>(
      h1b, 128, axv_bt, vbq, vbk, vbv, qv, kvb, vvb, QSC);
  qkv_gemm_kernel<64,64><<<dim3(2, NTOK/128), 256, 0, stream>>>(
      h1b, 192, axh_bt, hbq, hbk, hbv, qh, khb, vhb, QSC);
  loc_attn_mfma<<<4096, 256, 0, stream>>>(ql, klb, vlb, lbk, lbv, btbl, olb);
  axial_attn_kernel<<<896, 256, 0, stream>>>(qv, kvb, vvb, ovb, 1);
  axial_attn_kernel<<<896, 256, 0, stream>>>(qh, khb, vhb, ohb, 0);
  proj_res_ln2_kernel<<<NTOK / 4, 256, 0, stream>>>(x, olb, ovb, ohb,
                                                    lwp, lbp, vwp, vbp, hwp, hbp,
                                                    ln2w, ln2b, x2, n2);
  gemm1_gelu_kernel<<<dim3(HID / 128, NTOK / 128), 256, 0, stream>>>(n2, w1t, fc1b, hid);
  gemm2_res_kernel<<<dim3(CDIM / 128, NTOK / 128), 256, 0, stream>>>(hid, w2t, fc2b, x2);
}

// Round 5
// 809.493 us; speedup vs baseline: 6.8046x; 1.6601x over previous
//
#include <hip/hip_runtime.h>
#include <math.h>

// MixAxialPOLABlock — round 5: axial attention -> MFMA bf16
// (same two-phase structure as loc_attn: K + V^T staged in LDS once,
//  S in registers, softmax in registers, PV via wave-private P LDS chunk).

namespace {

constexpr int IMG  = 112;
constexpr int NTOK = 4 * IMG * IMG;   // 50176
constexpr int CDIM = 256;
constexpr int LCH  = 128;
constexpr int ACH  = 64;
constexpr int HID  = 1024;
constexpr float QSC = 0.17677669529663687f;  // 1/sqrt(32)

typedef __attribute__((ext_vector_type(8))) short bf16x8;
typedef __attribute__((ext_vector_type(4))) float f32x4;

__device__ inline short f2bf(float f) {
  union { float f; unsigned u; } c; c.f = f;
  unsigned u = c.u;
  return (short)((u + 0x7fffu + ((u >> 16) & 1u)) >> 16);
}

// ------------- weight transpose + bf16 convert: src[K][N] -> dst[N][K] -------------
__global__ __launch_bounds__(256) void conv_w_kernel(
    const float* __restrict__ src, short* __restrict__ dst, int K, int N)
{
  int idx = blockIdx.x * 256 + threadIdx.x;
  if (idx < K * N) {
    int n = idx / K, k = idx - n * K;
    dst[idx] = f2bf(src[(size_t)k * N + n]);
  }
}

// ---------------- LayerNorm (ln1) -> bf16 : one block per token ----------------
__global__ __launch_bounds__(256) void ln1_kernel(
    const float* __restrict__ x, const float* __restrict__ w,
    const float* __restrict__ b, short* __restrict__ out)
{
  int tok = blockIdx.x;
  int c = threadIdx.x;
  size_t idx = (size_t)tok * CDIM + c;
  float v = x[idx];
  float s = v, s2 = v * v;
  #pragma unroll
  for (int o = 32; o; o >>= 1) { s += __shfl_xor(s, o); s2 += __shfl_xor(s2, o); }
  __shared__ float red[8];
  int lane = c & 63, wv = c >> 6;
  if (lane == 0) { red[wv] = s; red[4 + wv] = s2; }
  __syncthreads();
  float a  = red[0] + red[1] + red[2] + red[3];
  float a2 = red[4] + red[5] + red[6] + red[7];
  float mu  = a * (1.f / CDIM);
  float var = a2 * (1.f / CDIM) - mu * mu;
  float rs  = rsqrtf(var + 1e-5f);
  out[idx] = f2bf((v - mu) * rs * w[c] + b[c]);
}

// ------------- q/k/v projection as bf16 MFMA GEMM -------------
template<int KD, int GD>
__global__ __launch_bounds__(256) void qkv_gemm_kernel(
    const short* __restrict__ h1b, int coff, const short* __restrict__ BT,
    const float* __restrict__ bq, const float* __restrict__ bk,
    const float* __restrict__ bv,
    float* __restrict__ qo, float* __restrict__ ko, float* __restrict__ vo,
    float qscale)
{
  __shared__ short a_lds[128 * 72];
  __shared__ short b_lds[128 * 72];
  int n0 = blockIdx.x * 128, m0 = blockIdx.y * 128;
  int tid = threadIdx.x;
  int lane = tid & 63, wv = tid >> 6;
  int g = lane >> 4, l15 = lane & 15;
  int wm = wv >> 1, wn = wv & 1;

  f32x4 acc[4][4];
  #pragma unroll
  for (int i = 0; i < 4; i++)
    #pragma unroll
    for (int j = 0; j < 4; j++) acc[i][j] = (f32x4){0.f, 0.f, 0.f, 0.f};

  for (int kb = 0; kb < KD; kb += 64) {
    __syncthreads();
    #pragma unroll
    for (int it = 0; it < 4; it++) {
      int i = tid + it * 256;
      int row = i >> 3, c8 = i & 7;
      *(bf16x8*)&a_lds[row * 72 + c8 * 8] =
          *(const bf16x8*)&h1b[(size_t)(m0 + row) * CDIM + coff + kb + c8 * 8];
      *(bf16x8*)&b_lds[row * 72 + c8 * 8] =
          *(const bf16x8*)&BT[(size_t)(n0 + row) * KD + kb + c8 * 8];
    }
    __syncthreads();
    #pragma unroll
    for (int ks = 0; ks < 2; ks++) {
      bf16x8 af[4], bfr[4];
      #pragma unroll
      for (int i = 0; i < 4; i++)
        af[i] = *(bf16x8*)&a_lds[(wm * 64 + i * 16 + l15) * 72 + ks * 32 + g * 8];
      #pragma unroll
      for (int j = 0; j < 4; j++)
        bfr[j] = *(bf16x8*)&b_lds[(wn * 64 + j * 16 + l15) * 72 + ks * 32 + g * 8];
      #pragma unroll
      for (int i = 0; i < 4; i++)
        #pragma unroll
        for (int j = 0; j < 4; j++)
          acc[i][j] = __builtin_amdgcn_mfma_f32_16x16x32_bf16(af[i], bfr[j], acc[i][j], 0, 0, 0);
    }
  }

  #pragma unroll
  for (int j = 0; j < 4; j++) {
    int ng = n0 + wn * 64 + j * 16 + l15;
    int sel = ng / GD;          // wave-uniform (GD is 64 or 128)
    int col = ng % GD;
    if (sel < 3) {
      float* op = sel == 0 ? qo : (sel == 1 ? ko : vo);
      const float* bp = sel == 0 ? bq : (sel == 1 ? bk : bv);
      float sc = sel == 0 ? qscale : 1.f;
      float bias = bp[col];
      #pragma unroll
      for (int i = 0; i < 4; i++) {
        #pragma unroll
        for (int r = 0; r < 4; r++) {
          int m = m0 + wm * 64 + i * 16 + g * 4 + r;
          op[(size_t)m * GD + col] = (acc[i][j][r] + bias) * sc;
        }
      }
    }
  }
}

// ---------------- local window attention, MFMA bf16 ----------------
__global__ __launch_bounds__(256) void loc_attn_mfma(
    const float* __restrict__ ql, const float* __restrict__ kl,
    const float* __restrict__ vl, const float* __restrict__ bk,
    const float* __restrict__ bv, const float* __restrict__ btbl,
    float* __restrict__ ol)
{
  constexpr int KSTR = 40;
  constexpr int VSTR = 456;
  constexpr int PSTR = 40;
  __shared__ short kv_lds[448 * KSTR];
  __shared__ float bias_lds[736];
  __shared__ short p_lds[4][16 * PSTR];

  int head = blockIdx.x & 3;
  int wi = blockIdx.x >> 2;
  int wx = wi & 15, wy = (wi >> 4) & 15, b = wi >> 8;
  int tid = threadIdx.x;
  int lane = tid & 63, wv = tid >> 6;
  int g = lane >> 4, l15 = lane & 15;
  const float* bkh = bk + head * 32;
  const float* bvh = bv + head * 32;

  for (int it = tid; it < 448 * 4; it += 256) {
    int key = it >> 2, dg = it & 3;
    float buf[8];
    if (key < 441) {
      int ky = key / 21, kx = key - ky * 21;
      int rr = wy * 7 + ky - 7, cc = wx * 7 + kx - 7;
      const float* src;
      if ((unsigned)rr < (unsigned)IMG && (unsigned)cc < (unsigned)IMG)
        src = kl + ((size_t)((b * IMG + rr) * IMG + cc)) * LCH + head * 32 + dg * 8;
      else
        src = bkh + dg * 8;
      float4 a0 = *(const float4*)src;
      float4 a1 = *(const float4*)(src + 4);
      buf[0] = a0.x; buf[1] = a0.y; buf[2] = a0.z; buf[3] = a0.w;
      buf[4] = a1.x; buf[5] = a1.y; buf[6] = a1.z; buf[7] = a1.w;
    } else {
      #pragma unroll
      for (int j = 0; j < 8; j++) buf[j] = 0.f;
    }
    bf16x8 f;
    #pragma unroll
    for (int j = 0; j < 8; j++) f[j] = f2bf(buf[j]);
    *(bf16x8*)(&kv_lds[key * KSTR + dg * 8]) = f;
  }
  for (int i = tid; i < 729; i += 256) bias_lds[i] = btbl[i * 4 + head];

  int q0 = wv * 16 + l15;
  int qc = q0 < 49 ? q0 : 48;
  int qy0 = qc / 7, qx0 = qc - qy0 * 7;
  size_t qbase = ((size_t)((b * IMG + wy * 7 + qy0) * IMG + wx * 7 + qx0)) * LCH
                 + head * 32 + g * 8;
  float4 qa = *(const float4*)(ql + qbase);
  float4 qb = *(const float4*)(ql + qbase + 4);
  bf16x8 qfrag;
  qfrag[0] = f2bf(qa.x); qfrag[1] = f2bf(qa.y); qfrag[2] = f2bf(qa.z); qfrag[3] = f2bf(qa.w);
  qfrag[4] = f2bf(qb.x); qfrag[5] = f2bf(qb.y); qfrag[6] = f2bf(qb.z); qfrag[7] = f2bf(qb.w);

  __syncthreads();

  f32x4 acc[28];
  #pragma unroll
  for (int n = 0; n < 28; n++) {
    bf16x8 kfrag = *(bf16x8*)(&kv_lds[(n * 16 + l15) * KSTR + g * 8]);
    f32x4 z = {0.f, 0.f, 0.f, 0.f};
    acc[n] = __builtin_amdgcn_mfma_f32_16x16x32_bf16(qfrag, kfrag, z, 0, 0, 0);
  }

  float rinv[4];
  #pragma unroll
  for (int r = 0; r < 4; r++) {
    int q = wv * 16 + g * 4 + r;
    int qq = q < 49 ? q : 0;
    int qy = qq / 7, qx = qq - qy * 7;
    float m = -1e30f;
    #pragma unroll
    for (int n = 0; n < 28; n++) {
      int key = n * 16 + l15;
      if (key < 441) {
        int ky = key / 21, kx = key - ky * 21;
        float s = acc[n][r] + bias_lds[(qy - ky + 20) * 27 + (qx - kx + 20)];
        acc[n][r] = s;
        m = fmaxf(m, s);
      } else {
        acc[n][r] = -1e30f;
      }
    }
    m = fmaxf(m, __shfl_xor(m, 1));
    m = fmaxf(m, __shfl_xor(m, 2));
    m = fmaxf(m, __shfl_xor(m, 4));
    m = fmaxf(m, __shfl_xor(m, 8));
    float sum = 0.f;
    #pragma unroll
    for (int n = 0; n < 28; n++) {
      float p = (acc[n][r] > -1e29f) ? __expf(acc[n][r] - m) : 0.f;
      acc[n][r] = p;
      sum += p;
    }
    sum += __shfl_xor(sum, 1);
    sum += __shfl_xor(sum, 2);
    sum += __shfl_xor(sum, 4);
    sum += __shfl_xor(sum, 8);
    rinv[r] = 1.f / sum;
  }

  __syncthreads();

  for (int it = tid; it < 448 * 4; it += 256) {
    int key = it >> 2, dg = it & 3;
    float buf[8];
    if (key < 441) {
      int ky = key / 21, kx = key - ky * 21;
      int rr = wy * 7 + ky - 7, cc = wx * 7 + kx - 7;
      const float* src;
      if ((unsigned)rr < (unsigned)IMG && (unsigned)cc < (unsigned)IMG)
        src = vl + ((size_t)((b * IMG + rr) * IMG + cc)) * LCH + head * 32 + dg * 8;
      else
        src = bvh + dg * 8;
      float4 a0 = *(const float4*)src;
      float4 a1 = *(const float4*)(src + 4);
      buf[0] = a0.x; buf[1] = a0.y; buf[2] = a0.z; buf[3] = a0.w;
      buf[4] = a1.x; buf[5] = a1.y; buf[6] = a1.z; buf[7] = a1.w;
    } else {
      #pragma unroll
      for (int j = 0; j < 8; j++) buf[j] = 0.f;
    }
    #pragma unroll
    for (int j = 0; j < 8; j++) kv_lds[(dg * 8 + j) * VSTR + key] = f2bf(buf[j]);
  }
  __syncthreads();

  f32x4 oacc[2];
  oacc[0] = (f32x4){0.f, 0.f, 0.f, 0.f};
  oacc[1] = (f32x4){0.f, 0.f, 0.f, 0.f};
  short* pw = p_lds[wv];
  #pragma unroll
  for (int c = 0; c < 14; c++) {
    #pragma unroll
    for (int t = 0; t < 2; t++) {
      f32x4 pv = acc[2 * c + t];
      #pragma unroll
      for (int r = 0; r < 4; r++)
        pw[(g * 4 + r) * PSTR + t * 16 + l15] = f2bf(pv[r]);
    }
    asm volatile("s_waitcnt lgkmcnt(0)" ::: "memory");
    bf16x8 pfrag = *(bf16x8*)(&pw[l15 * PSTR + g * 8]);
    #pragma unroll
    for (int nt = 0; nt < 2; nt++) {
      bf16x8 vfrag = *(bf16x8*)(&kv_lds[(nt * 16 + l15) * VSTR + c * 32 + g * 8]);
      oacc[nt] = __builtin_amdgcn_mfma_f32_16x16x32_bf16(pfrag, vfrag, oacc[nt], 0, 0, 0);
    }
  }

  #pragma unroll
  for (int r = 0; r < 4; r++) {
    int q = wv * 16 + g * 4 + r;
    if (q < 49) {
      int qy = q / 7, qx = q - qy * 7;
      size_t obase = ((size_t)((b * IMG + wy * 7 + qy) * IMG + wx * 7 + qx)) * LCH
                     + head * 32;
      ol[obase + l15]      = oacc[0][r] * rinv[r];
      ol[obase + 16 + l15] = oacc[1][r] * rinv[r];
    }
  }
}

// ---------------- axial attention, MFMA bf16 ----------------
// block = (sequence, head); seq len 112 = 7 M-tiles of 16, keys padded to 128.
// Stage K (128 x KSTR) and V^T (32 x VSTR) once; each wave processes M-tiles
// {wv, wv+4} fully in registers (7 QK^T MFMAs -> softmax -> 4x2 PV MFMAs).
__global__ __launch_bounds__(256) void axial_attn_mfma(
    const float* __restrict__ q, const float* __restrict__ k,
    const float* __restrict__ v, float* __restrict__ out, int vert)
{
  constexpr int KSTR = 40;    // K row stride (shorts)
  constexpr int VSTR = 136;   // V^T row stride (shorts): 128 keys + 8 pad
  constexpr int PSTR = 40;
  __shared__ short k_lds[128 * KSTR];    // 10240 B
  __shared__ short vt_lds[32 * VSTR];    // 8704 B
  __shared__ short p_lds[4][16 * PSTR];  // 5120 B

  int head = blockIdx.x & 1;
  int s = blockIdx.x >> 1;
  int b = s / IMG, t = s % IMG;
  size_t base; int stride;
  if (vert) { base = ((size_t)b * IMG * IMG + t) * ACH; stride = IMG * ACH; }
  else      { base = ((size_t)(b * IMG + t)) * (size_t)IMG * ACH; stride = ACH; }
  base += head * 32;

  int tid = threadIdx.x;
  int lane = tid & 63, wv = tid >> 6;
  int g = lane >> 4, l15 = lane & 15;

  // ---- stage K (rows >=112 zero) and V^T in one pass ----
  for (int it = tid; it < 128 * 4; it += 256) {
    int key = it >> 2, dg = it & 3;
    float kb[8], vb[8];
    if (key < IMG) {
      const float* ks = k + base + (size_t)key * stride + dg * 8;
      const float* vs = v + base + (size_t)key * stride + dg * 8;
      float4 a0 = *(const float4*)ks;
      float4 a1 = *(const float4*)(ks + 4);
      float4 b0 = *(const float4*)vs;
      float4 b1 = *(const float4*)(vs + 4);
      kb[0] = a0.x; kb[1] = a0.y; kb[2] = a0.z; kb[3] = a0.w;
      kb[4] = a1.x; kb[5] = a1.y; kb[6] = a1.z; kb[7] = a1.w;
      vb[0] = b0.x; vb[1] = b0.y; vb[2] = b0.z; vb[3] = b0.w;
      vb[4] = b1.x; vb[5] = b1.y; vb[6] = b1.z; vb[7] = b1.w;
    } else {
      #pragma unroll
      for (int j = 0; j < 8; j++) { kb[j] = 0.f; vb[j] = 0.f; }
    }
    bf16x8 kf;
    #pragma unroll
    for (int j = 0; j < 8; j++) kf[j] = f2bf(kb[j]);
    *(bf16x8*)(&k_lds[key * KSTR + dg * 8]) = kf;
    #pragma unroll
    for (int j = 0; j < 8; j++) vt_lds[(dg * 8 + j) * VSTR + key] = f2bf(vb[j]);
  }
  __syncthreads();

  short* pw = p_lds[wv];
  #pragma unroll 1
  for (int mi = 0; mi < 2; mi++) {
    int mt = wv + mi * 4;
    if (mt >= 7) break;    // wave 3 has one tile; no barriers below
    // Q A-fragment
    int qrow = mt * 16 + l15;
    const float* qs = q + base + (size_t)qrow * stride + g * 8;
    float4 qa = *(const float4*)qs;
    float4 qb2 = *(const float4*)(qs + 4);
    bf16x8 qfrag;
    qfrag[0] = f2bf(qa.x);  qfrag[1] = f2bf(qa.y);  qfrag[2] = f2bf(qa.z);  qfrag[3] = f2bf(qa.w);
    qfrag[4] = f2bf(qb2.x); qfrag[5] = f2bf(qb2.y); qfrag[6] = f2bf(qb2.z); qfrag[7] = f2bf(qb2.w);

    // S = Q.K^T over 7 N-tiles (112 keys exactly, no masking)
    f32x4 acc[7];
    #pragma unroll
    for (int n = 0; n < 7; n++) {
      bf16x8 kfrag = *(bf16x8*)(&k_lds[(n * 16 + l15) * KSTR + g * 8]);
      f32x4 z = {0.f, 0.f, 0.f, 0.f};
      acc[n] = __builtin_amdgcn_mfma_f32_16x16x32_bf16(qfrag, kfrag, z, 0, 0, 0);
    }

    // softmax (row reduce over the 16-lane column group)
    float rinv[4];
    #pragma unroll
    for (int r = 0; r < 4; r++) {
      float m = -1e30f;
      #pragma unroll
      for (int n = 0; n < 7; n++) m = fmaxf(m, acc[n][r]);
      m = fmaxf(m, __shfl_xor(m, 1));
      m = fmaxf(m, __shfl_xor(m, 2));
      m = fmaxf(m, __shfl_xor(m, 4));
      m = fmaxf(m, __shfl_xor(m, 8));
      float sum = 0.f;
      #pragma unroll
      for (int n = 0; n < 7; n++) {
        float p = __expf(acc[n][r] - m);
        acc[n][r] = p;
        sum += p;
      }
      sum += __shfl_xor(sum, 1);
      sum += __shfl_xor(sum, 2);
      sum += __shfl_xor(sum, 4);
      sum += __shfl_xor(sum, 8);
      rinv[r] = 1.f / sum;
    }

    // O = P.V : 4 chunks of 32 keys (chunk-tile 7 = zero pad)
    f32x4 oacc[2];
    oacc[0] = (f32x4){0.f, 0.f, 0.f, 0.f};
    oacc[1] = (f32x4){0.f, 0.f, 0.f, 0.f};
    #pragma unroll
    for (int c = 0; c < 4; c++) {
      #pragma unroll
      for (int t2 = 0; t2 < 2; t2++) {
        int n = 2 * c + t2;
        if (n < 7) {
          f32x4 pv = acc[n];
          #pragma unroll
          for (int r = 0; r < 4; r++)
            pw[(g * 4 + r) * PSTR + t2 * 16 + l15] = f2bf(pv[r]);
        } else {
          #pragma unroll
          for (int r = 0; r < 4; r++)
            pw[(g * 4 + r) * PSTR + t2 * 16 + l15] = 0;
        }
      }
      asm volatile("s_waitcnt lgkmcnt(0)" ::: "memory");
      bf16x8 pfrag = *(bf16x8*)(&pw[l15 * PSTR + g * 8]);
      #pragma unroll
      for (int nt = 0; nt < 2; nt++) {
        bf16x8 vfrag = *(bf16x8*)(&vt_lds[(nt * 16 + l15) * VSTR + c * 32 + g * 8]);
        oacc[nt] = __builtin_amdgcn_mfma_f32_16x16x32_bf16(pfrag, vfrag, oacc[nt], 0, 0, 0);
      }
    }

    // store (fold 1/sum)
    #pragma unroll
    for (int r = 0; r < 4; r++) {
      int qq = mt * 16 + g * 4 + r;   // < 112 always
      float* op = out + base + (size_t)qq * stride;
      op[l15]      = oacc[0][r] * rinv[r];
      op[16 + l15] = oacc[1][r] * rinv[r];
    }
  }
}

// ------ output projections + residual concat -> x2 (d_out) + fused LN2 -> n2 bf16 ------
__global__ __launch_bounds__(256) void proj_res_ln2_kernel(
    const float* __restrict__ x, const float* __restrict__ ol,
    const float* __restrict__ ov, const float* __restrict__ oh,
    const float* __restrict__ wpl, const float* __restrict__ bpl,
    const float* __restrict__ wpv, const float* __restrict__ bpv,
    const float* __restrict__ wph, const float* __restrict__ bph,
    const float* __restrict__ lw, const float* __restrict__ lb,
    float* __restrict__ x2, short* __restrict__ n2)
{
  constexpr int TM = 4;
  __shared__ float rl[TM][LCH];
  __shared__ float rv[TM][ACH];
  __shared__ float rh[TM][ACH];
  __shared__ float red[8][TM];
  int t0 = blockIdx.x * TM;
  for (int i = threadIdx.x; i < TM * LCH; i += 256) {
    int t = i >> 7, c = i & 127;
    rl[t][c] = ol[(size_t)(t0 + t) * LCH + c];
  }
  for (int i = threadIdx.x; i < TM * ACH; i += 256) {
    int t = i >> 6, c = i & 63;
    rv[t][c] = ov[(size_t)(t0 + t) * ACH + c];
    rh[t][c] = oh[(size_t)(t0 + t) * ACH + c];
  }
  __syncthreads();
  int c = threadIdx.x;
  float acc[TM];
  if (c < 128) {
    #pragma unroll
    for (int t = 0; t < TM; t++) acc[t] = bpl[c];
    for (int kk = 0; kk < LCH; kk++) {
      float wval = wpl[(size_t)kk * LCH + c];
      #pragma unroll
      for (int t = 0; t < TM; t++) acc[t] += rl[t][kk] * wval;
    }
  } else if (c < 192) {
    int cc = c - 128;
    #pragma unroll
    for (int t = 0; t < TM; t++) acc[t] = bpv[cc];
    for (int kk = 0; kk < ACH; kk++) {
      float wval = wpv[(size_t)kk * ACH + cc];
      #pragma unroll
      for (int t = 0; t < TM; t++) acc[t] += rv[t][kk] * wval;
    }
  } else {
    int cc = c - 192;
    #pragma unroll
    for (int t = 0; t < TM; t++) acc[t] = bph[cc];
    for (int kk = 0; kk < ACH; kk++) {
      float wval = wph[(size_t)kk * ACH + cc];
      #pragma unroll
      for (int t = 0; t < TM; t++) acc[t] += rh[t][kk] * wval;
    }
  }
  float vals[TM];
  #pragma unroll
  for (int t = 0; t < TM; t++) {
    size_t idx = (size_t)(t0 + t) * CDIM + c;
    vals[t] = x[idx] + acc[t];
    x2[idx] = vals[t];
  }
  int lane = c & 63, wvid = c >> 6;
  float s[TM], s2[TM];
  #pragma unroll
  for (int t = 0; t < TM; t++) { s[t] = vals[t]; s2[t] = vals[t] * vals[t]; }
  #pragma unroll
  for (int o = 32; o; o >>= 1) {
    #pragma unroll
    for (int t = 0; t < TM; t++) { s[t] += __shfl_xor(s[t], o); s2[t] += __shfl_xor(s2[t], o); }
  }
  if (lane == 0) {
    #pragma unroll
    for (int t = 0; t < TM; t++) { red[wvid][t] = s[t]; red[4 + wvid][t] = s2[t]; }
  }
  __syncthreads();
  #pragma unroll
  for (int t = 0; t < TM; t++) {
    float a  = red[0][t] + red[1][t] + red[2][t] + red[3][t];
    float a2 = red[4][t] + red[5][t] + red[6][t] + red[7][t];
    float mu  = a * (1.f / CDIM);
    float var = a2 * (1.f / CDIM) - mu * mu;
    float rs  = rsqrtf(var + 1e-5f);
    n2[(size_t)(t0 + t) * CDIM + c] = f2bf((vals[t] - mu) * rs * lw[c] + lb[c]);
  }
}

// ---------------- GEMM1: hid = GELU(n2 @ W1 + b1), bf16 MFMA ----------------
__global__ __launch_bounds__(256) void gemm1_gelu_kernel(
    const short* __restrict__ A, const short* __restrict__ BT,
    const float* __restrict__ b1, short* __restrict__ hid)
{
  constexpr int K = 256;
  __shared__ short a_lds[128 * 72];
  __shared__ short b_lds[128 * 72];
  int n0 = blockIdx.x * 128, m0 = blockIdx.y * 128;
  int tid = threadIdx.x;
  int lane = tid & 63, wv = tid >> 6;
  int g = lane >> 4, l15 = lane & 15;
  int wm = wv >> 1, wn = wv & 1;

  f32x4 acc[4][4];
  #pragma unroll
  for (int i = 0; i < 4; i++)
    #pragma unroll
    for (int j = 0; j < 4; j++) acc[i][j] = (f32x4){0.f, 0.f, 0.f, 0.f};

  for (int kb = 0; kb < K; kb += 64) {
    __syncthreads();
    #pragma unroll
    for (int it = 0; it < 4; it++) {
      int i = tid + it * 256;
      int row = i >> 3, c8 = i & 7;
      *(bf16x8*)&a_lds[row * 72 + c8 * 8] =
          *(const bf16x8*)&A[(size_t)(m0 + row) * K + kb + c8 * 8];
      *(bf16x8*)&b_lds[row * 72 + c8 * 8] =
          *(const bf16x8*)&BT[(size_t)(n0 + row) * K + kb + c8 * 8];
    }
    __syncthreads();
    #pragma unroll
    for (int ks = 0; ks < 2; ks++) {
      bf16x8 af[4], bfr[4];
      #pragma unroll
      for (int i = 0; i < 4; i++)
        af[i] = *(bf16x8*)&a_lds[(wm * 64 + i * 16 + l15) * 72 + ks * 32 + g * 8];
      #pragma unroll
      for (int j = 0; j < 4; j++)
        bfr[j] = *(bf16x8*)&b_lds[(wn * 64 + j * 16 + l15) * 72 + ks * 32 + g * 8];
      #pragma unroll
      for (int i = 0; i < 4; i++)
        #pragma unroll
        for (int j = 0; j < 4; j++)
          acc[i][j] = __builtin_amdgcn_mfma_f32_16x16x32_bf16(af[i], bfr[j], acc[i][j], 0, 0, 0);
    }
  }

  #pragma unroll
  for (int j = 0; j < 4; j++) {
    int n = n0 + wn * 64 + j * 16 + l15;
    float bias = b1[n];
    #pragma unroll
    for (int i = 0; i < 4; i++) {
      #pragma unroll
      for (int r = 0; r < 4; r++) {
        int m = m0 + wm * 64 + i * 16 + g * 4 + r;
        float h = acc[i][j][r] + bias;
        h = 0.5f * h * (1.f + erff(h * 0.70710678118654752f));
        hid[(size_t)m * HID + n] = f2bf(h);
      }
    }
  }
}

// ---------------- GEMM2: out = x2 + hid @ W2 + b2, bf16 MFMA ----------------
__global__ __launch_bounds__(256) void gemm2_res_kernel(
    const short* __restrict__ A, const short* __restrict__ BT,
    const float* __restrict__ b2, float* __restrict__ out)
{
  constexpr int K = 1024;
  __shared__ short a_lds[128 * 72];
  __shared__ short b_lds[128 * 72];
  int n0 = blockIdx.x * 128, m0 = blockIdx.y * 128;
  int tid = threadIdx.x;
  int lane = tid & 63, wv = tid >> 6;
  int g = lane >> 4, l15 = lane & 15;
  int wm = wv >> 1, wn = wv & 1;

  f32x4 acc[4][4];
  #pragma unroll
  for (int i = 0; i < 4; i++)
    #pragma unroll
    for (int j = 0; j < 4; j++) acc[i][j] = (f32x4){0.f, 0.f, 0.f, 0.f};

  for (int kb = 0; kb < K; kb += 64) {
    __syncthreads();
    #pragma unroll
    for (int it = 0; it < 4; it++) {
      int i = tid + it * 256;
      int row = i >> 3, c8 = i & 7;
      *(bf16x8*)&a_lds[row * 72 + c8 * 8] =
          *(const bf16x8*)&A[(size_t)(m0 + row) * K + kb + c8 * 8];
      *(bf16x8*)&b_lds[row * 72 + c8 * 8] =
          *(const bf16x8*)&BT[(size_t)(n0 + row) * K + kb + c8 * 8];
    }
    __syncthreads();
    #pragma unroll
    for (int ks = 0; ks < 2; ks++) {
      bf16x8 af[4], bfr[4];
      #pragma unroll
      for (int i = 0; i < 4; i++)
        af[i] = *(bf16x8*)&a_lds[(wm * 64 + i * 16 + l15) * 72 + ks * 32 + g * 8];
      #pragma unroll
      for (int j = 0; j < 4; j++)
        bfr[j] = *(bf16x8*)&b_lds[(wn * 64 + j * 16 + l15) * 72 + ks * 32 + g * 8];
      #pragma unroll
      for (int i = 0; i < 4; i++)
        #pragma unroll
        for (int j = 0; j < 4; j++)
          acc[i][j] = __builtin_amdgcn_mfma_f32_16x16x32_bf16(af[i], bfr[j], acc[i][j], 0, 0, 0);
    }
  }

  #pragma unroll
  for (int j = 0; j < 4; j++) {
    int n = n0 + wn * 64 + j * 16 + l15;
    float bias = b2[n];
    #pragma unroll
    for (int i = 0; i < 4; i++) {
      #pragma unroll
      for (int r = 0; r < 4; r++) {
        int m = m0 + wm * 64 + i * 16 + g * 4 + r;
        size_t idx = (size_t)m * CDIM + n;
        out[idx] = out[idx] + acc[i][j][r] + bias;
      }
    }
  }
}

}  // namespace

extern "C" void kernel_launch(void* const* d_in, const int* in_sizes, int n_in,
                              void* d_out, int out_size, void* d_ws, size_t ws_size,
                              hipStream_t stream)
{
  const float* x    = (const float*)d_in[0];
  const float* ln1w = (const float*)d_in[3];
  const float* ln1b = (const float*)d_in[4];
  const float* ln2w = (const float*)d_in[5];
  const float* ln2b = (const float*)d_in[6];
  const float* btbl = (const float*)d_in[7];
  const float* lwq  = (const float*)d_in[8];
  const float* lbq  = (const float*)d_in[9];
  const float* lwk  = (const float*)d_in[10];
  const float* lbk  = (const float*)d_in[11];
  const float* lwv  = (const float*)d_in[12];
  const float* lbv  = (const float*)d_in[13];
  const float* lwp  = (const float*)d_in[14];
  const float* lbp  = (const float*)d_in[15];
  const float* vwq  = (const float*)d_in[16];
  const float* vbq  = (const float*)d_in[17];
  const float* vwk  = (const float*)d_in[18];
  const float* vbk  = (const float*)d_in[19];
  const float* vwv  = (const float*)d_in[20];
  const float* vbv  = (const float*)d_in[21];
  const float* vwp  = (const float*)d_in[22];
  const float* vbp  = (const float*)d_in[23];
  const float* hwq  = (const float*)d_in[24];
  const float* hbq  = (const float*)d_in[25];
  const float* hwk  = (const float*)d_in[26];
  const float* hbk  = (const float*)d_in[27];
  const float* hwv  = (const float*)d_in[28];
  const float* hbv  = (const float*)d_in[29];
  const float* hwp  = (const float*)d_in[30];
  const float* hbp  = (const float*)d_in[31];
  const float* fc1w = (const float*)d_in[32];
  const float* fc1b = (const float*)d_in[33];
  const float* fc2w = (const float*)d_in[34];
  const float* fc2b = (const float*)d_in[35];

  float* ws = (float*)d_ws;
  size_t off = 0;
  auto alloc = [&](size_t n) { float* p = ws + off; off += n; return p; };
  float* h1f = alloc((size_t)NTOK * CDIM);
  float* ql  = alloc((size_t)NTOK * LCH);
  float* klb = alloc((size_t)NTOK * LCH);
  float* vlb = alloc((size_t)NTOK * LCH);
  float* olb = alloc((size_t)NTOK * LCH);
  float* qv  = alloc((size_t)NTOK * ACH);
  float* kvb = alloc((size_t)NTOK * ACH);
  float* vvb = alloc((size_t)NTOK * ACH);
  float* ovb = alloc((size_t)NTOK * ACH);
  float* qh  = alloc((size_t)NTOK * ACH);
  float* khb = alloc((size_t)NTOK * ACH);
  float* vhb = alloc((size_t)NTOK * ACH);
  float* ohb = alloc((size_t)NTOK * ACH);
  short* w1t    = (short*)(ws + off);
  short* w2t    = w1t + (size_t)CDIM * HID;
  short* loc_bt = w2t + (size_t)CDIM * HID;
  short* axv_bt = loc_bt + 384 * 128;
  short* axh_bt = axv_bt + 256 * 64;
  short* h1b = (short*)h1f;
  short* n2  = (short*)ws;
  short* hid = n2 + (size_t)NTOK * CDIM;
  float* x2  = (float*)d_out;

  conv_w_kernel<<<(CDIM * HID + 255) / 256, 256, 0, stream>>>(fc1w, w1t, CDIM, HID);
  conv_w_kernel<<<(CDIM * HID + 255) / 256, 256, 0, stream>>>(fc2w, w2t, HID, CDIM);
  conv_w_kernel<<<64, 256, 0, stream>>>(lwq, loc_bt,            128, 128);
  conv_w_kernel<<<64, 256, 0, stream>>>(lwk, loc_bt + 128*128,  128, 128);
  conv_w_kernel<<<64, 256, 0, stream>>>(lwv, loc_bt + 2*128*128,128, 128);
  conv_w_kernel<<<16, 256, 0, stream>>>(vwq, axv_bt,            64, 64);
  conv_w_kernel<<<16, 256, 0, stream>>>(vwk, axv_bt + 64*64,    64, 64);
  conv_w_kernel<<<16, 256, 0, stream>>>(vwv, axv_bt + 2*64*64,  64, 64);
  conv_w_kernel<<<16, 256, 0, stream>>>(hwq, axh_bt,            64, 64);
  conv_w_kernel<<<16, 256, 0, stream>>>(hwk, axh_bt + 64*64,    64, 64);
  conv_w_kernel<<<16, 256, 0, stream>>>(hwv, axh_bt + 2*64*64,  64, 64);

  ln1_kernel<<<NTOK, 256, 0, stream>>>(x, ln1w, ln1b, h1b);
  qkv_gemm_kernel<128,128><<<dim3(3, NTOK/128), 256, 0, stream>>>(
      h1b, 0, loc_bt, lbq, lbk, lbv, ql, klb, vlb, QSC);
  qkv_gemm_kernel<64,64><<<dim3(2, NTOK/128), 256, 0, stream>>>(
      h1b, 128, axv_bt, vbq, vbk, vbv, qv, kvb, vvb, QSC);
  qkv_gemm_kernel<64,64><<<dim3(2, NTOK/128), 256, 0, stream>>>(
      h1b, 192, axh_bt, hbq, hbk, hbv, qh, khb, vhb, QSC);
  loc_attn_mfma<<<4096, 256, 0, stream>>>(ql, klb, vlb, lbk, lbv, btbl, olb);
  axial_attn_mfma<<<896, 256, 0, stream>>>(qv, kvb, vvb, ovb, 1);
  axial_attn_mfma<<<896, 256, 0, stream>>>(qh, khb, vhb, ohb, 0);
  proj_res_ln2_kernel<<<NTOK / 4, 256, 0, stream>>>(x, olb, ovb, ohb,
                                                    lwp, lbp, vwp, vbp, hwp, hbp,
                                                    ln2w, ln2b, x2, n2);
  gemm1_gelu_kernel<<<dim3(HID / 128, NTOK / 128), 256, 0, stream>>>(n2, w1t, fc1b, hid);
  gemm2_res_kernel<<<dim3(CDIM / 128, NTOK / 128), 256, 0, stream>>>(hid, w2t, fc2b, x2);
}

// Round 7
// 718.260 us; speedup vs baseline: 7.6689x; 1.1270x over previous
//
#include <hip/hip_runtime.h>
#include <math.h>

// MixAxialPOLABlock — round 6b (syntax fix of round 6):
//  * q/k/v stored bf16 (qkv_gemm epilogue emits bf16) -> attention staging is
//    pure 16B copies, no per-element f32->bf16 conversion.
//  * loc/axial V-transpose: key-pair packed b32 LDS writes, kp-major lane map
//    (conflict-free per m136); VSTR=464/136 keeps b128 reads 16B-aligned.
//  * attention outputs -> combined bf16 att[NTOK][256]; output projections
//    become one block-diagonal 256x256 bf16 MFMA GEMM with fused residual+LN2.

namespace {

constexpr int IMG  = 112;
constexpr int NTOK = 4 * IMG * IMG;   // 50176
constexpr int CDIM = 256;
constexpr int LCH  = 128;
constexpr int ACH  = 64;
constexpr int HID  = 1024;
constexpr float QSC = 0.17677669529663687f;  // 1/sqrt(32)

typedef __attribute__((ext_vector_type(8))) short bf16x8;
typedef __attribute__((ext_vector_type(4))) float f32x4;

__device__ inline short f2bf(float f) {
  union { float f; unsigned u; } c; c.f = f;
  unsigned u = c.u;
  return (short)((u + 0x7fffu + ((u >> 16) & 1u)) >> 16);
}

// ------------- weight transpose + bf16 convert: src[K][N] -> dst[N][K] -------------
// (K=1 degenerates to a plain bf16 convert of a length-N vector.)
__global__ __launch_bounds__(256) void conv_w_kernel(
    const float* __restrict__ src, short* __restrict__ dst, int K, int N)
{
  int idx = blockIdx.x * 256 + threadIdx.x;
  if (idx < K * N) {
    int n = idx / K, k = idx - n * K;
    dst[idx] = f2bf(src[(size_t)k * N + n]);
  }
}

// ------------- block-diagonal projection weight builder: BT[256][256] + pbias ------
__global__ __launch_bounds__(256) void proj_w_kernel(
    const float* __restrict__ wpl, const float* __restrict__ wpv,
    const float* __restrict__ wph,
    const float* __restrict__ bpl, const float* __restrict__ bpv,
    const float* __restrict__ bph,
    short* __restrict__ BT, float* __restrict__ pbias)
{
  int idx = blockIdx.x * 256 + threadIdx.x;   // 65536
  int n = idx >> 8, k = idx & 255;
  float v = 0.f;
  if (n < 128)      { if (k < 128)             v = wpl[(size_t)k * 128 + n]; }
  else if (n < 192) { if (k >= 128 && k < 192) v = wpv[(size_t)(k - 128) * 64 + (n - 128)]; }
  else              { if (k >= 192)            v = wph[(size_t)(k - 192) * 64 + (n - 192)]; }
  BT[idx] = f2bf(v);
  if (idx < 256)
    pbias[idx] = idx < 128 ? bpl[idx] : (idx < 192 ? bpv[idx - 128] : bph[idx - 192]);
}

// ---------------- LayerNorm (ln1) -> bf16 : one block per token ----------------
__global__ __launch_bounds__(256) void ln1_kernel(
    const float* __restrict__ x, const float* __restrict__ w,
    const float* __restrict__ b, short* __restrict__ out)
{
  int tok = blockIdx.x;
  int c = threadIdx.x;
  size_t idx = (size_t)tok * CDIM + c;
  float v = x[idx];
  float s = v, s2 = v * v;
  #pragma unroll
  for (int o = 32; o; o >>= 1) { s += __shfl_xor(s, o); s2 += __shfl_xor(s2, o); }
  __shared__ float red[8];
  int lane = c & 63, wv = c >> 6;
  if (lane == 0) { red[wv] = s; red[4 + wv] = s2; }
  __syncthreads();
  float a  = red[0] + red[1] + red[2] + red[3];
  float a2 = red[4] + red[5] + red[6] + red[7];
  float mu  = a * (1.f / CDIM);
  float var = a2 * (1.f / CDIM) - mu * mu;
  float rs  = rsqrtf(var + 1e-5f);
  out[idx] = f2bf((v - mu) * rs * w[c] + b[c]);
}

// ------------- q/k/v projection as bf16 MFMA GEMM (bf16 outputs) -------------
template<int KD, int GD>
__global__ __launch_bounds__(256) void qkv_gemm_kernel(
    const short* __restrict__ h1b, int coff, const short* __restrict__ BT,
    const float* __restrict__ bq, const float* __restrict__ bk,
    const float* __restrict__ bv,
    short* __restrict__ qo, short* __restrict__ ko, short* __restrict__ vo,
    float qscale)
{
  __shared__ short a_lds[128 * 72];
  __shared__ short b_lds[128 * 72];
  int n0 = blockIdx.x * 128, m0 = blockIdx.y * 128;
  int tid = threadIdx.x;
  int lane = tid & 63, wv = tid >> 6;
  int g = lane >> 4, l15 = lane & 15;
  int wm = wv >> 1, wn = wv & 1;

  f32x4 acc[4][4];
  #pragma unroll
  for (int i = 0; i < 4; i++)
    #pragma unroll
    for (int j = 0; j < 4; j++) acc[i][j] = (f32x4){0.f, 0.f, 0.f, 0.f};

  for (int kb = 0; kb < KD; kb += 64) {
    __syncthreads();
    #pragma unroll
    for (int it = 0; it < 4; it++) {
      int i = tid + it * 256;
      int row = i >> 3, c8 = i & 7;
      *(bf16x8*)&a_lds[row * 72 + c8 * 8] =
          *(const bf16x8*)&h1b[(size_t)(m0 + row) * CDIM + coff + kb + c8 * 8];
      *(bf16x8*)&b_lds[row * 72 + c8 * 8] =
          *(const bf16x8*)&BT[(size_t)(n0 + row) * KD + kb + c8 * 8];
    }
    __syncthreads();
    #pragma unroll
    for (int ks = 0; ks < 2; ks++) {
      bf16x8 af[4], bfr[4];
      #pragma unroll
      for (int i = 0; i < 4; i++)
        af[i] = *(bf16x8*)&a_lds[(wm * 64 + i * 16 + l15) * 72 + ks * 32 + g * 8];
      #pragma unroll
      for (int j = 0; j < 4; j++)
        bfr[j] = *(bf16x8*)&b_lds[(wn * 64 + j * 16 + l15) * 72 + ks * 32 + g * 8];
      #pragma unroll
      for (int i = 0; i < 4; i++)
        #pragma unroll
        for (int j = 0; j < 4; j++)
          acc[i][j] = __builtin_amdgcn_mfma_f32_16x16x32_bf16(af[i], bfr[j], acc[i][j], 0, 0, 0);
    }
  }

  #pragma unroll
  for (int j = 0; j < 4; j++) {
    int ng = n0 + wn * 64 + j * 16 + l15;
    int sel = ng / GD;          // wave-uniform
    int col = ng % GD;
    if (sel < 3) {
      short* op = sel == 0 ? qo : (sel == 1 ? ko : vo);
      const float* bp = sel == 0 ? bq : (sel == 1 ? bk : bv);
      float sc = sel == 0 ? qscale : 1.f;
      float bias = bp[col];
      #pragma unroll
      for (int i = 0; i < 4; i++) {
        #pragma unroll
        for (int r = 0; r < 4; r++) {
          int m = m0 + wm * 64 + i * 16 + g * 4 + r;
          op[(size_t)m * GD + col] = f2bf((acc[i][j][r] + bias) * sc);
        }
      }
    }
  }
}

// ---------------- local window attention, MFMA bf16 (bf16 in, bf16 out) ----------------
__global__ __launch_bounds__(256) void loc_attn_mfma(
    const short* __restrict__ ql, const short* __restrict__ kl,
    const short* __restrict__ vl, const short* __restrict__ bkb,
    const short* __restrict__ bvb, const float* __restrict__ btbl,
    short* __restrict__ att)
{
  constexpr int KSTR = 40;
  constexpr int VSTR = 464;   // 928 B rows: 16B-aligned b128 reads
  constexpr int PSTR = 40;
  __shared__ short kv_lds[448 * KSTR];   // K rows; later V^T (32 x VSTR fits)
  __shared__ float bias_lds[736];
  __shared__ short p_lds[4][16 * PSTR];

  int head = blockIdx.x & 3;
  int wi = blockIdx.x >> 2;
  int wx = wi & 15, wy = (wi >> 4) & 15, b = wi >> 8;
  int tid = threadIdx.x;
  int lane = tid & 63, wv = tid >> 6;
  int g = lane >> 4, l15 = lane & 15;
  int hoff = head * 32;

  // ---- stage K (bf16 copy) + bias head-slice ----
  for (int it = tid; it < 448 * 4; it += 256) {
    int key = it >> 2, dg = it & 3;
    bf16x8 f;
    if (key < 441) {
      int ky = key / 21, kx = key - ky * 21;
      int rr = wy * 7 + ky - 7, cc = wx * 7 + kx - 7;
      if ((unsigned)rr < (unsigned)IMG && (unsigned)cc < (unsigned)IMG)
        f = *(const bf16x8*)&kl[((size_t)((b * IMG + rr) * IMG + cc)) * LCH + hoff + dg * 8];
      else
        f = *(const bf16x8*)&bkb[hoff + dg * 8];
    } else {
      #pragma unroll
      for (int j = 0; j < 8; j++) f[j] = 0;
    }
    *(bf16x8*)(&kv_lds[key * KSTR + dg * 8]) = f;
  }
  for (int i = tid; i < 729; i += 256) bias_lds[i] = btbl[i * 4 + head];

  // ---- Q A-fragment: single 16B bf16 load ----
  int q0 = wv * 16 + l15;
  int qc = q0 < 49 ? q0 : 48;
  int qy0 = qc / 7, qx0 = qc - qy0 * 7;
  bf16x8 qfrag = *(const bf16x8*)&ql[((size_t)((b * IMG + wy * 7 + qy0) * IMG + wx * 7 + qx0))
                                     * LCH + hoff + g * 8];

  __syncthreads();

  // ---- S = Q.K^T ----
  f32x4 acc[28];
  #pragma unroll
  for (int n = 0; n < 28; n++) {
    bf16x8 kfrag = *(bf16x8*)(&kv_lds[(n * 16 + l15) * KSTR + g * 8]);
    f32x4 z = {0.f, 0.f, 0.f, 0.f};
    acc[n] = __builtin_amdgcn_mfma_f32_16x16x32_bf16(qfrag, kfrag, z, 0, 0, 0);
  }

  float rinv[4];
  #pragma unroll
  for (int r = 0; r < 4; r++) {
    int q = wv * 16 + g * 4 + r;
    int qq = q < 49 ? q : 0;
    int qy = qq / 7, qx = qq - qy * 7;
    float m = -1e30f;
    #pragma unroll
    for (int n = 0; n < 28; n++) {
      int key = n * 16 + l15;
      if (key < 441) {
        int ky = key / 21, kx = key - ky * 21;
        float s = acc[n][r] + bias_lds[(qy - ky + 20) * 27 + (qx - kx + 20)];
        acc[n][r] = s;
        m = fmaxf(m, s);
      } else {
        acc[n][r] = -1e30f;
      }
    }
    m = fmaxf(m, __shfl_xor(m, 1));
    m = fmaxf(m, __shfl_xor(m, 2));
    m = fmaxf(m, __shfl_xor(m, 4));
    m = fmaxf(m, __shfl_xor(m, 8));
    float sum = 0.f;
    #pragma unroll
    for (int n = 0; n < 28; n++) {
      float p = (acc[n][r] > -1e29f) ? __expf(acc[n][r] - m) : 0.f;
      acc[n][r] = p;
      sum += p;
    }
    sum += __shfl_xor(sum, 1);
    sum += __shfl_xor(sum, 2);
    sum += __shfl_xor(sum, 4);
    sum += __shfl_xor(sum, 8);
    rinv[r] = 1.f / sum;
  }

  __syncthreads();   // all waves done with K region

  // ---- stage V^T: key-pair packed b32 writes, kp-major lane mapping ----
  for (int it = tid; it < 896; it += 256) {
    int dg = it / 224;
    int kp = it - dg * 224;
    int key0 = kp * 2, key1 = key0 + 1;
    bf16x8 v0, v1;
    {
      int ky = key0 / 21, kx = key0 - ky * 21;
      int rr = wy * 7 + ky - 7, cc = wx * 7 + kx - 7;
      if ((unsigned)rr < (unsigned)IMG && (unsigned)cc < (unsigned)IMG)
        v0 = *(const bf16x8*)&vl[((size_t)((b * IMG + rr) * IMG + cc)) * LCH + hoff + dg * 8];
      else
        v0 = *(const bf16x8*)&bvb[hoff + dg * 8];
    }
    if (key1 < 441) {
      int ky = key1 / 21, kx = key1 - ky * 21;
      int rr = wy * 7 + ky - 7, cc = wx * 7 + kx - 7;
      if ((unsigned)rr < (unsigned)IMG && (unsigned)cc < (unsigned)IMG)
        v1 = *(const bf16x8*)&vl[((size_t)((b * IMG + rr) * IMG + cc)) * LCH + hoff + dg * 8];
      else
        v1 = *(const bf16x8*)&bvb[hoff + dg * 8];
    } else {
      #pragma unroll
      for (int j = 0; j < 8; j++) v1[j] = 0;
    }
    #pragma unroll
    for (int j = 0; j < 8; j++) {
      unsigned w = (unsigned short)v0[j] | ((unsigned)(unsigned short)v1[j] << 16);
      *(unsigned*)&kv_lds[(dg * 8 + j) * VSTR + key0] = w;
    }
  }
  __syncthreads();

  // ---- O = P.V ----
  f32x4 oacc[2];
  oacc[0] = (f32x4){0.f, 0.f, 0.f, 0.f};
  oacc[1] = (f32x4){0.f, 0.f, 0.f, 0.f};
  short* pw = p_lds[wv];
  #pragma unroll
  for (int c = 0; c < 14; c++) {
    #pragma unroll
    for (int t = 0; t < 2; t++) {
      f32x4 pv = acc[2 * c + t];
      #pragma unroll
      for (int r = 0; r < 4; r++)
        pw[(g * 4 + r) * PSTR + t * 16 + l15] = f2bf(pv[r]);
    }
    asm volatile("s_waitcnt lgkmcnt(0)" ::: "memory");
    bf16x8 pfrag = *(bf16x8*)(&pw[l15 * PSTR + g * 8]);
    #pragma unroll
    for (int nt = 0; nt < 2; nt++) {
      bf16x8 vfrag = *(bf16x8*)(&kv_lds[(nt * 16 + l15) * VSTR + c * 32 + g * 8]);
      oacc[nt] = __builtin_amdgcn_mfma_f32_16x16x32_bf16(pfrag, vfrag, oacc[nt], 0, 0, 0);
    }
  }

  // ---- store O (bf16) into combined att buffer, cols [head*32, head*32+32) ----
  #pragma unroll
  for (int r = 0; r < 4; r++) {
    int q = wv * 16 + g * 4 + r;
    if (q < 49) {
      int qy = q / 7, qx = q - qy * 7;
      size_t obase = ((size_t)((b * IMG + wy * 7 + qy) * IMG + wx * 7 + qx)) * CDIM + hoff;
      att[obase + l15]      = f2bf(oacc[0][r] * rinv[r]);
      att[obase + 16 + l15] = f2bf(oacc[1][r] * rinv[r]);
    }
  }
}

// ---------------- axial attention, MFMA bf16 (bf16 in, bf16 out) ----------------
__global__ __launch_bounds__(256) void axial_attn_mfma(
    const short* __restrict__ q, const short* __restrict__ k,
    const short* __restrict__ v, short* __restrict__ att, int vert, int coff)
{
  constexpr int KSTR = 40;
  constexpr int VSTR = 136;   // 272 B: 16B-aligned
  constexpr int PSTR = 40;
  __shared__ short k_lds[128 * KSTR];
  __shared__ short vt_lds[32 * VSTR];
  __shared__ short p_lds[4][16 * PSTR];

  int head = blockIdx.x & 1;
  int s = blockIdx.x >> 1;
  int b = s / IMG, t = s % IMG;
  size_t base; int stride;
  if (vert) { base = ((size_t)b * IMG * IMG + t) * ACH; stride = IMG * ACH; }
  else      { base = ((size_t)(b * IMG + t)) * (size_t)IMG * ACH; stride = ACH; }
  base += head * 32;

  int tid = threadIdx.x;
  int lane = tid & 63, wv = tid >> 6;
  int g = lane >> 4, l15 = lane & 15;

  // ---- stage K (rows >=112 zero) ----
  for (int it = tid; it < 512; it += 256) {
    int key = it >> 2, dg = it & 3;
    bf16x8 f;
    if (key < IMG) {
      f = *(const bf16x8*)&k[base + (size_t)key * stride + dg * 8];
    } else {
      #pragma unroll
      for (int j = 0; j < 8; j++) f[j] = 0;
    }
    *(bf16x8*)(&k_lds[key * KSTR + dg * 8]) = f;
  }
  // ---- stage V^T: one key-pair b32 write per thread (kp-major) ----
  {
    int dg = tid >> 6, kp = tid & 63;
    int key0 = kp * 2, key1 = key0 + 1;
    bf16x8 v0, v1;
    if (key0 < IMG) {
      v0 = *(const bf16x8*)&v[base + (size_t)key0 * stride + dg * 8];
    } else {
      #pragma unroll
      for (int j = 0; j < 8; j++) v0[j] = 0;
    }
    if (key1 < IMG) {
      v1 = *(const bf16x8*)&v[base + (size_t)key1 * stride + dg * 8];
    } else {
      #pragma unroll
      for (int j = 0; j < 8; j++) v1[j] = 0;
    }
    #pragma unroll
    for (int j = 0; j < 8; j++) {
      unsigned w = (unsigned short)v0[j] | ((unsigned)(unsigned short)v1[j] << 16);
      *(unsigned*)&vt_lds[(dg * 8 + j) * VSTR + key0] = w;
    }
  }
  __syncthreads();

  short* pw = p_lds[wv];
  #pragma unroll 1
  for (int mi = 0; mi < 2; mi++) {
    int mt = wv + mi * 4;
    if (mt >= 7) break;
    int qrow = mt * 16 + l15;
    bf16x8 qfrag = *(const bf16x8*)&q[base + (size_t)qrow * stride + g * 8];

    f32x4 acc[7];
    #pragma unroll
    for (int n = 0; n < 7; n++) {
      bf16x8 kfrag = *(bf16x8*)(&k_lds[(n * 16 + l15) * KSTR + g * 8]);
      f32x4 z = {0.f, 0.f, 0.f, 0.f};
      acc[n] = __builtin_amdgcn_mfma_f32_16x16x32_bf16(qfrag, kfrag, z, 0, 0, 0);
    }

    float rinv[4];
    #pragma unroll
    for (int r = 0; r < 4; r++) {
      float m = -1e30f;
      #pragma unroll
      for (int n = 0; n < 7; n++) m = fmaxf(m, acc[n][r]);
      m = fmaxf(m, __shfl_xor(m, 1));
      m = fmaxf(m, __shfl_xor(m, 2));
      m = fmaxf(m, __shfl_xor(m, 4));
      m = fmaxf(m, __shfl_xor(m, 8));
      float sum = 0.f;
      #pragma unroll
      for (int n = 0; n < 7; n++) {
        float p = __expf(acc[n][r] - m);
        acc[n][r] = p;
        sum += p;
      }
      sum += __shfl_xor(sum, 1);
      sum += __shfl_xor(sum, 2);
      sum += __shfl_xor(sum, 4);
      sum += __shfl_xor(sum, 8);
      rinv[r] = 1.f / sum;
    }

    f32x4 oacc[2];
    oacc[0] = (f32x4){0.f, 0.f, 0.f, 0.f};
    oacc[1] = (f32x4){0.f, 0.f, 0.f, 0.f};
    #pragma unroll
    for (int c = 0; c < 4; c++) {
      #pragma unroll
      for (int t2 = 0; t2 < 2; t2++) {
        int n = 2 * c + t2;
        if (n < 7) {
          f32x4 pv = acc[n];
          #pragma unroll
          for (int r = 0; r < 4; r++)
            pw[(g * 4 + r) * PSTR + t2 * 16 + l15] = f2bf(pv[r]);
        } else {
          #pragma unroll
          for (int r = 0; r < 4; r++)
            pw[(g * 4 + r) * PSTR + t2 * 16 + l15] = 0;
        }
      }
      asm volatile("s_waitcnt lgkmcnt(0)" ::: "memory");
      bf16x8 pfrag = *(bf16x8*)(&pw[l15 * PSTR + g * 8]);
      #pragma unroll
      for (int nt = 0; nt < 2; nt++) {
        bf16x8 vfrag = *(bf16x8*)(&vt_lds[(nt * 16 + l15) * VSTR + c * 32 + g * 8]);
        oacc[nt] = __builtin_amdgcn_mfma_f32_16x16x32_bf16(pfrag, vfrag, oacc[nt], 0, 0, 0);
      }
    }

    #pragma unroll
    for (int r = 0; r < 4; r++) {
      int qq = mt * 16 + g * 4 + r;
      int token = vert ? (b * IMG + qq) * IMG + t : (b * IMG + t) * IMG + qq;
      short* op = att + (size_t)token * CDIM + coff + head * 32;
      op[l15]      = f2bf(oacc[0][r] * rinv[r]);
      op[16 + l15] = f2bf(oacc[1][r] * rinv[r]);
    }
  }
}

// ------ proj GEMM (block-diag 256x256) + residual + LN2, MFMA bf16 ------
// Block: 64 rows x 256 cols (N un-split so LN2 reduces fully in-wave).
__global__ __launch_bounds__(256) void proj_gemm_ln2_kernel(
    const short* __restrict__ att, const short* __restrict__ BT,
    const float* __restrict__ pbias, const float* __restrict__ x,
    const float* __restrict__ lw, const float* __restrict__ lb,
    float* __restrict__ x2, short* __restrict__ n2)
{
  __shared__ short a_lds[64 * 72];
  __shared__ short b_lds[256 * 72];
  __shared__ float lw_s[256], lb_s[256], pb_s[256];
  int m0 = blockIdx.x * 64;
  int tid = threadIdx.x;
  int lane = tid & 63, wv = tid >> 6;
  int g = lane >> 4, l15 = lane & 15;
  if (tid < 256) { lw_s[tid] = lw[tid]; lb_s[tid] = lb[tid]; pb_s[tid] = pbias[tid]; }

  f32x4 acc[16];
  #pragma unroll
  for (int n = 0; n < 16; n++) acc[n] = (f32x4){0.f, 0.f, 0.f, 0.f};

  for (int kb = 0; kb < 256; kb += 64) {
    __syncthreads();
    #pragma unroll
    for (int it = 0; it < 2; it++) {
      int i = tid + it * 256;                    // 512 = 64 rows x 8 chunks
      int row = i >> 3, c8 = i & 7;
      *(bf16x8*)&a_lds[row * 72 + c8 * 8] =
          *(const bf16x8*)&att[(size_t)(m0 + row) * CDIM + kb + c8 * 8];
    }
    #pragma unroll
    for (int it = 0; it < 8; it++) {
      int i = tid + it * 256;                    // 2048 = 256 rows x 8 chunks
      int row = i >> 3, c8 = i & 7;
      *(bf16x8*)&b_lds[row * 72 + c8 * 8] =
          *(const bf16x8*)&BT[(size_t)row * CDIM + kb + c8 * 8];
    }
    __syncthreads();
    #pragma unroll
    for (int ks = 0; ks < 2; ks++) {
      bf16x8 af = *(bf16x8*)&a_lds[(wv * 16 + l15) * 72 + ks * 32 + g * 8];
      #pragma unroll
      for (int n = 0; n < 16; n++) {
        bf16x8 bfr = *(bf16x8*)&b_lds[(n * 16 + l15) * 72 + ks * 32 + g * 8];
        acc[n] = __builtin_amdgcn_mfma_f32_16x16x32_bf16(af, bfr, acc[n], 0, 0, 0);
      }
    }
  }

  // epilogue: vals = acc + pbias + x; LN2 over the 256-col row (in-wave)
  #pragma unroll
  for (int r = 0; r < 4; r++) {
    int m = m0 + wv * 16 + g * 4 + r;
    float vals[16];
    float sum = 0.f, sum2 = 0.f;
    #pragma unroll
    for (int n = 0; n < 16; n++) {
      int col = n * 16 + l15;
      float sv = acc[n][r] + pb_s[col] + x[(size_t)m * CDIM + col];
      vals[n] = sv;
      sum += sv;
      sum2 += sv * sv;
    }
    sum  += __shfl_xor(sum, 1);  sum2 += __shfl_xor(sum2, 1);
    sum  += __shfl_xor(sum, 2);  sum2 += __shfl_xor(sum2, 2);
    sum  += __shfl_xor(sum, 4);  sum2 += __shfl_xor(sum2, 4);
    sum  += __shfl_xor(sum, 8);  sum2 += __shfl_xor(sum2, 8);
    float mu  = sum * (1.f / CDIM);
    float var = sum2 * (1.f / CDIM) - mu * mu;
    float rs  = rsqrtf(var + 1e-5f);
    #pragma unroll
    for (int n = 0; n < 16; n++) {
      int col = n * 16 + l15;
      x2[(size_t)m * CDIM + col] = vals[n];
      n2[(size_t)m * CDIM + col] = f2bf((vals[n] - mu) * rs * lw_s[col] + lb_s[col]);
    }
  }
}

// ---------------- GEMM1: hid = GELU(n2 @ W1 + b1), bf16 MFMA ----------------
__global__ __launch_bounds__(256) void gemm1_gelu_kernel(
    const short* __restrict__ A, const short* __restrict__ BT,
    const float* __restrict__ b1, short* __restrict__ hid)
{
  constexpr int K = 256;
  __shared__ short a_lds[128 * 72];
  __shared__ short b_lds[128 * 72];
  int n0 = blockIdx.x * 128, m0 = blockIdx.y * 128;
  int tid = threadIdx.x;
  int lane = tid & 63, wv = tid >> 6;
  int g = lane >> 4, l15 = lane & 15;
  int wm = wv >> 1, wn = wv & 1;

  f32x4 acc[4][4];
  #pragma unroll
  for (int i = 0; i < 4; i++)
    #pragma unroll
    for (int j = 0; j < 4; j++) acc[i][j] = (f32x4){0.f, 0.f, 0.f, 0.f};

  for (int kb = 0; kb < K; kb += 64) {
    __syncthreads();
    #pragma unroll
    for (int it = 0; it < 4; it++) {
      int i = tid + it * 256;
      int row = i >> 3, c8 = i & 7;
      *(bf16x8*)&a_lds[row * 72 + c8 * 8] =
          *(const bf16x8*)&A[(size_t)(m0 + row) * K + kb + c8 * 8];
      *(bf16x8*)&b_lds[row * 72 + c8 * 8] =
          *(const bf16x8*)&BT[(size_t)(n0 + row) * K + kb + c8 * 8];
    }
    __syncthreads();
    #pragma unroll
    for (int ks = 0; ks < 2; ks++) {
      bf16x8 af[4], bfr[4];
      #pragma unroll
      for (int i = 0; i < 4; i++)
        af[i] = *(bf16x8*)&a_lds[(wm * 64 + i * 16 + l15) * 72 + ks * 32 + g * 8];
      #pragma unroll
      for (int j = 0; j < 4; j++)
        bfr[j] = *(bf16x8*)&b_lds[(wn * 64 + j * 16 + l15) * 72 + ks * 32 + g * 8];
      #pragma unroll
      for (int i = 0; i < 4; i++)
        #pragma unroll
        for (int j = 0; j < 4; j++)
          acc[i][j] = __builtin_amdgcn_mfma_f32_16x16x32_bf16(af[i], bfr[j], acc[i][j], 0, 0, 0);
    }
  }

  #pragma unroll
  for (int j = 0; j < 4; j++) {
    int n = n0 + wn * 64 + j * 16 + l15;
    float bias = b1[n];
    #pragma unroll
    for (int i = 0; i < 4; i++) {
      #pragma unroll
      for (int r = 0; r < 4; r++) {
        int m = m0 + wm * 64 + i * 16 + g * 4 + r;
        float h = acc[i][j][r] + bias;
        h = 0.5f * h * (1.f + erff(h * 0.70710678118654752f));
        hid[(size_t)m * HID + n] = f2bf(h);
      }
    }
  }
}

// ---------------- GEMM2: out = x2 + hid @ W2 + b2, bf16 MFMA ----------------
__global__ __launch_bounds__(256) void gemm2_res_kernel(
    const short* __restrict__ A, const short* __restrict__ BT,
    const float* __restrict__ b2, float* __restrict__ out)
{
  constexpr int K = 1024;
  __shared__ short a_lds[128 * 72];
  __shared__ short b_lds[128 * 72];
  int n0 = blockIdx.x * 128, m0 = blockIdx.y * 128;
  int tid = threadIdx.x;
  int lane = tid & 63, wv = tid >> 6;
  int g = lane >> 4, l15 = lane & 15;
  int wm = wv >> 1, wn = wv & 1;

  f32x4 acc[4][4];
  #pragma unroll
  for (int i = 0; i < 4; i++)
    #pragma unroll
    for (int j = 0; j < 4; j++) acc[i][j] = (f32x4){0.f, 0.f, 0.f, 0.f};

  for (int kb = 0; kb < K; kb += 64) {
    __syncthreads();
    #pragma unroll
    for (int it = 0; it < 4; it++) {
      int i = tid + it * 256;
      int row = i >> 3, c8 = i & 7;
      *(bf16x8*)&a_lds[row * 72 + c8 * 8] =
          *(const bf16x8*)&A[(size_t)(m0 + row) * K + kb + c8 * 8];
      *(bf16x8*)&b_lds[row * 72 + c8 * 8] =
          *(const bf16x8*)&BT[(size_t)(n0 + row) * K + kb + c8 * 8];
    }
    __syncthreads();
    #pragma unroll
    for (int ks = 0; ks < 2; ks++) {
      bf16x8 af[4], bfr[4];
      #pragma unroll
      for (int i = 0; i < 4; i++)
        af[i] = *(bf16x8*)&a_lds[(wm * 64 + i * 16 + l15) * 72 + ks * 32 + g * 8];
      #pragma unroll
      for (int j = 0; j < 4; j++)
        bfr[j] = *(bf16x8*)&b_lds[(wn * 64 + j * 16 + l15) * 72 + ks * 32 + g * 8];
      #pragma unroll
      for (int i = 0; i < 4; i++)
        #pragma unroll
        for (int j = 0; j < 4; j++)
          acc[i][j] = __builtin_amdgcn_mfma_f32_16x16x32_bf16(af[i], bfr[j], acc[i][j], 0, 0, 0);
    }
  }

  #pragma unroll
  for (int j = 0; j < 4; j++) {
    int n = n0 + wn * 64 + j * 16 + l15;
    float bias = b2[n];
    #pragma unroll
    for (int i = 0; i < 4; i++) {
      #pragma unroll
      for (int r = 0; r < 4; r++) {
        int m = m0 + wm * 64 + i * 16 + g * 4 + r;
        size_t idx = (size_t)m * CDIM + n;
        out[idx] = out[idx] + acc[i][j][r] + bias;
      }
    }
  }
}

}  // namespace

extern "C" void kernel_launch(void* const* d_in, const int* in_sizes, int n_in,
                              void* d_out, int out_size, void* d_ws, size_t ws_size,
                              hipStream_t stream)
{
  const float* x    = (const float*)d_in[0];
  const float* ln1w = (const float*)d_in[3];
  const float* ln1b = (const float*)d_in[4];
  const float* ln2w = (const float*)d_in[5];
  const float* ln2b = (const float*)d_in[6];
  const float* btbl = (const float*)d_in[7];
  const float* lwq  = (const float*)d_in[8];
  const float* lbq  = (const float*)d_in[9];
  const float* lwk  = (const float*)d_in[10];
  const float* lbk  = (const float*)d_in[11];
  const float* lwv  = (const float*)d_in[12];
  const float* lbv  = (const float*)d_in[13];
  const float* lwp  = (const float*)d_in[14];
  const float* lbp  = (const float*)d_in[15];
  const float* vwq  = (const float*)d_in[16];
  const float* vbq  = (const float*)d_in[17];
  const float* vwk  = (const float*)d_in[18];
  const float* vbk  = (const float*)d_in[19];
  const float* vwv  = (const float*)d_in[20];
  const float* vbv  = (const float*)d_in[21];
  const float* vwp  = (const float*)d_in[22];
  const float* vbp  = (const float*)d_in[23];
  const float* hwq  = (const float*)d_in[24];
  const float* hbq  = (const float*)d_in[25];
  const float* hwk  = (const float*)d_in[26];
  const float* hbk  = (const float*)d_in[27];
  const float* hwv  = (const float*)d_in[28];
  const float* hbv  = (const float*)d_in[29];
  const float* hwp  = (const float*)d_in[30];
  const float* hbp  = (const float*)d_in[31];
  const float* fc1w = (const float*)d_in[32];
  const float* fc1b = (const float*)d_in[33];
  const float* fc2w = (const float*)d_in[34];
  const float* fc2b = (const float*)d_in[35];

  float* ws = (float*)d_ws;
  size_t off = 0;
  auto alloc = [&](size_t n) { float* p = ws + off; off += n; return p; };
  float* h1f = alloc((size_t)NTOK * CDIM);   // region 0: h1b / att / n2 (bf16)
  float* qls = alloc((size_t)NTOK * LCH);    // regions 1-4: bf16 q/k/v + hid alias
  float* kls = alloc((size_t)NTOK * LCH);
  float* vls = alloc((size_t)NTOK * LCH);
  float* spare = alloc((size_t)NTOK * LCH);
  float* qvs = alloc((size_t)NTOK * ACH);
  float* kvs = alloc((size_t)NTOK * ACH);
  float* vvs = alloc((size_t)NTOK * ACH);
  float* qhs = alloc((size_t)NTOK * ACH);
  float* khs = alloc((size_t)NTOK * ACH);
  float* vhs = alloc((size_t)NTOK * ACH);
  (void)spare;
  // bf16 weight/const buffers at tail
  short* w1t     = (short*)(ws + off);                 // [1024][256]
  short* w2t     = w1t + (size_t)CDIM * HID;           // [256][1024]
  short* loc_bt  = w2t + (size_t)CDIM * HID;           // [384][128]
  short* axv_bt  = loc_bt + 384 * 128;                 // [192][64]
  short* axh_bt  = axv_bt + 192 * 64;                  // [192][64]
  short* bt_proj = axh_bt + 192 * 64;                  // [256][256]
  short* bkb     = bt_proj + 256 * 256;                // [128]
  short* bvb     = bkb + 128;                          // [128]
  float* pbias   = (float*)(bvb + 128);                // [256]
  // bf16 activation aliases
  short* h1b = (short*)h1f;                            // [NTOK][256]
  short* att = (short*)h1f;                            // [NTOK][256] (after qkv reads done)
  short* n2  = att + (size_t)NTOK * CDIM;              // [NTOK][256] (2nd half of region 0)
  short* qlb = (short*)qls; short* klb = (short*)kls; short* vlb = (short*)vls;
  short* qvb = (short*)qvs; short* kvb = (short*)kvs; short* vvb = (short*)vvs;
  short* qhb = (short*)qhs; short* khb = (short*)khs; short* vhb = (short*)vhs;
  short* hid = (short*)qls;                            // [NTOK][1024] spans regions 1-4
  float* x2  = (float*)d_out;

  // weight prep
  conv_w_kernel<<<(CDIM * HID + 255) / 256, 256, 0, stream>>>(fc1w, w1t, CDIM, HID);
  conv_w_kernel<<<(CDIM * HID + 255) / 256, 256, 0, stream>>>(fc2w, w2t, HID, CDIM);
  conv_w_kernel<<<64, 256, 0, stream>>>(lwq, loc_bt,             128, 128);
  conv_w_kernel<<<64, 256, 0, stream>>>(lwk, loc_bt + 128*128,   128, 128);
  conv_w_kernel<<<64, 256, 0, stream>>>(lwv, loc_bt + 2*128*128, 128, 128);
  conv_w_kernel<<<16, 256, 0, stream>>>(vwq, axv_bt,             64, 64);
  conv_w_kernel<<<16, 256, 0, stream>>>(vwk, axv_bt + 64*64,     64, 64);
  conv_w_kernel<<<16, 256, 0, stream>>>(vwv, axv_bt + 2*64*64,   64, 64);
  conv_w_kernel<<<16, 256, 0, stream>>>(hwq, axh_bt,             64, 64);
  conv_w_kernel<<<16, 256, 0, stream>>>(hwk, axh_bt + 64*64,     64, 64);
  conv_w_kernel<<<16, 256, 0, stream>>>(hwv, axh_bt + 2*64*64,   64, 64);
  conv_w_kernel<<<1, 256, 0, stream>>>(lbk, bkb, 1, 128);
  conv_w_kernel<<<1, 256, 0, stream>>>(lbv, bvb, 1, 128);
  proj_w_kernel<<<256, 256, 0, stream>>>(lwp, vwp, hwp, lbp, vbp, hbp, bt_proj, pbias);

  ln1_kernel<<<NTOK, 256, 0, stream>>>(x, ln1w, ln1b, h1b);
  qkv_gemm_kernel<128,128><<<dim3(3, NTOK/128), 256, 0, stream>>>(
      h1b, 0, loc_bt, lbq, lbk, lbv, qlb, klb, vlb, QSC);
  qkv_gemm_kernel<64,64><<<dim3(2, NTOK/128), 256, 0, stream>>>(
      h1b, 128, axv_bt, vbq, vbk, vbv, qvb, kvb, vvb, QSC);
  qkv_gemm_kernel<64,64><<<dim3(2, NTOK/128), 256, 0, stream>>>(
      h1b, 192, axh_bt, hbq, hbk, hbv, qhb, khb, vhb, QSC);
  loc_attn_mfma<<<4096, 256, 0, stream>>>(qlb, klb, vlb, bkb, bvb, btbl, att);
  axial_attn_mfma<<<896, 256, 0, stream>>>(qvb, kvb, vvb, att, 1, 128);
  axial_attn_mfma<<<896, 256, 0, stream>>>(qhb, khb, vhb, att, 0, 192);
  proj_gemm_ln2_kernel<<<NTOK / 64, 256, 0, stream>>>(att, bt_proj, pbias, x,
                                                      ln2w, ln2b, x2, n2);
  gemm1_gelu_kernel<<<dim3(HID / 128, NTOK / 128), 256, 0, stream>>>(n2, w1t, fc1b, hid);
  gemm2_res_kernel<<<dim3(CDIM / 128, NTOK / 128), 256, 0, stream>>>(hid, w2t, fc2b, x2);
}